// Round 4
// baseline (407.560 us; speedup 1.0000x reference)
//
#include <hip/hip_runtime.h>
#include <hip/hip_bf16.h>
#include <cstdint>

// Problem constants
#define Bb 8
#define SLh 512
#define Hh 768
#define NSs 256
#define Ww 32
#define NHh 12
#define HDd 64
#define FFN_I 3072
#define NTOK (Bb*SLh)      // 4096
#define NSPAN (Bb*NSs)     // 2048

typedef __attribute__((ext_vector_type(8))) __bf16 bf16x8;
typedef __attribute__((ext_vector_type(4))) float f32x4;

__device__ __forceinline__ short f2bf(float f) {
  unsigned u = __builtin_bit_cast(unsigned, f);
  unsigned r = (u + 0x7fffu + ((u >> 16) & 1u)) >> 16;
  return (short)r;
}
__device__ __forceinline__ float bflo(unsigned u) { return __builtin_bit_cast(float, u << 16); }
__device__ __forceinline__ float bfhi(unsigned u) { return __builtin_bit_cast(float, u & 0xffff0000u); }

// ---------------- tok = token_reps + pos_encoding, cast bf16 ----------------
__global__ __launch_bounds__(192) void tok_kernel(const float* __restrict__ tr,
                                                  short* __restrict__ tok) {
  int row = blockIdx.x;            // 4096 = b*512+s
  int s = row & (SLh - 1);
  int c0 = threadIdx.x * 4;        // 192 threads * 4 = 768
  float4 v = *(const float4*)(tr + (size_t)row * Hh + c0);
  const float kinv = -9.210340371976184f / (float)Hh;  // -ln(10000)/H
  float f0 = __expf((float)c0 * kinv);
  float f1 = __expf((float)(c0 + 2) * kinv);
  float s0, cc0, s1, cc1;
  __sincosf((float)s * f0, &s0, &cc0);
  __sincosf((float)s * f1, &s1, &cc1);
  v.x += s0; v.y += cc0; v.z += s1; v.w += cc1;
  short4 o{f2bf(v.x), f2bf(v.y), f2bf(v.z), f2bf(v.w)};
  *(short4*)(tok + (size_t)row * Hh + c0) = o;
}

// ---------------- fused f32 -> bf16 cast of the 4 weight matrices ----------------
__global__ __launch_bounds__(256) void cast4(const float* __restrict__ s0,
                                             const float* __restrict__ s1,
                                             const float* __restrict__ s2,
                                             const float* __restrict__ s3,
                                             short* __restrict__ d0,
                                             short* __restrict__ d1,
                                             short* __restrict__ d2,
                                             short* __restrict__ d3) {
  int b = blockIdx.x;
  const float* s; short* d; int off;
  if (b < 1152)      { s = s0; d = d0; off = b; }
  else if (b < 1728) { s = s1; d = d1; off = b - 1152; }
  else if (b < 4032) { s = s2; d = d2; off = b - 1728; }
  else               { s = s3; d = d3; off = b - 4032; }
  int i = off * 256 + threadIdx.x;
  float4 v = ((const float4*)s)[i];
  short4 o{f2bf(v.x), f2bf(v.y), f2bf(v.z), f2bf(v.w)};
  ((short4*)d)[i] = o;
}

// ---------------- q vector (scaled 1/8) and bias2 = out_proj_b + q0 ----------------
__global__ __launch_bounds__(64) void prep_qb(const float* __restrict__ dq,
                                              const float* __restrict__ ipw,
                                              const float* __restrict__ ipb,
                                              const float* __restrict__ opb,
                                              float* __restrict__ qsv,
                                              float* __restrict__ bias2) {
  int h = blockIdx.x * 64 + threadIdx.x;   // 12 blocks * 64 = 768
  const float4* wr = (const float4*)(ipw + (size_t)h * Hh);  // Wq rows 0..767
  const float4* qv = (const float4*)dq;
  float acc = 0.f;
  for (int j = 0; j < Hh / 4; ++j) {
    float4 w4 = wr[j], q4 = qv[j];
    acc += w4.x * q4.x + w4.y * q4.y + w4.z * q4.z + w4.w * q4.w;
  }
  acc += ipb[h];
  qsv[h] = acc * 0.125f;          // / sqrt(64)
  bias2[h] = opb[h] + dq[h];
}

// ---------------- bf16 MFMA GEMM, C = A(MxK) * Bt(NxK)^T ----------------
// 128x128 tile, BK=64, 256 threads (4 waves, 2x2 -> 64x64 wave tiles, 4x4 acc).
// Reg-staged pipeline (T14): linear coalesced global->VGPR loads issued one
// K-iter ahead; vmcnt(0) + XOR-swizzled ds_write_b128 after MFMA issue.
// LDS swizzle: 16B slot S of row R lives at S^(R&7)  (write AND read, G4 fix).
// Double-buffered LDS = 64 KB -> 2 blocks/CU.
// EPI 0: bf16 = acc+bias ; 1: bf16 = relu(acc+bias) ;
// EPI 3: f32 partial = acc into Cf + blockIdx.z*M*N (split-K).
template <int EPI>
__global__ __launch_bounds__(256, 2) void gemm_bt(const short* __restrict__ A,
                                                  const short* __restrict__ Bt,
                                                  const float* __restrict__ bias,
                                                  float* __restrict__ Cf,
                                                  short* __restrict__ Cb,
                                                  int M, int N, int ldk, int Kc) {
  __shared__ __align__(16) char Al[2][128 * 128];   // [buf][row*128 + slot*16]
  __shared__ __align__(16) char Bl[2][128 * 128];
  const int tid = threadIdx.x;
  const int lane = tid & 63, wave = tid >> 6;
  const int wm = wave >> 1, wn = wave & 1;           // 2x2 wave grid
  const int row0 = blockIdx.y * 128, col0 = blockIdx.x * 128;
  const int kbase = blockIdx.z * Kc;
  const int l15 = lane & 15, hi = lane >> 4;
  f32x4 acc[4][4] = {};
  const int nk = Kc >> 6;

  // staging geometry: pass j (j<4): row = j*32 + (tid>>3), 16B slot = tid&7.
  const int srow = tid >> 3, sslot = tid & 7;
  const size_t gAoff = (size_t)(row0 + srow) * ldk + kbase + sslot * 8;
  const size_t gBoff = (size_t)(col0 + srow) * ldk + kbase + sslot * 8;
  // LDS write byte offset for pass j's row
  int wby[4];
#pragma unroll
  for (int j = 0; j < 4; ++j) {
    int R = j * 32 + srow;
    wby[j] = R * 128 + ((sslot ^ (R & 7)) * 16);
  }

  int4 ra[4], rb[4];
  auto issue_loads = [&](int kt) {
#pragma unroll
    for (int j = 0; j < 4; ++j) {
      ra[j] = *(const int4*)(A + gAoff + (size_t)(j * 32) * ldk + kt * 64);
      rb[j] = *(const int4*)(Bt + gBoff + (size_t)(j * 32) * ldk + kt * 64);
    }
  };
  auto write_lds = [&](int bi) {
#pragma unroll
    for (int j = 0; j < 4; ++j) {
      *(int4*)(&Al[bi][0] + wby[j]) = ra[j];
      *(int4*)(&Bl[bi][0] + wby[j]) = rb[j];
    }
  };

  // prologue
  issue_loads(0);
  asm volatile("s_waitcnt vmcnt(0)" ::: "memory");
  write_lds(0);

  int cur = 0;
  for (int kt = 0; kt < nk; ++kt) {
    __syncthreads();                       // LDS[cur] ready for everyone
    if (kt + 1 < nk) issue_loads(kt + 1);  // linear coalesced prefetch
    bf16x8 fa[2][4], fb[2][4];
#pragma unroll
    for (int kk = 0; kk < 2; ++kk) {
      const int s = kk * 4 + hi;           // logical 16B slot 0..7
#pragma unroll
      for (int i = 0; i < 4; ++i) {
        int Ra = wm * 64 + i * 16 + l15;
        fa[kk][i] = *(const bf16x8*)(&Al[cur][0] + Ra * 128 + ((s ^ (Ra & 7)) * 16));
        int Rb = wn * 64 + i * 16 + l15;
        fb[kk][i] = *(const bf16x8*)(&Bl[cur][0] + Rb * 128 + ((s ^ (Rb & 7)) * 16));
      }
    }
#pragma unroll
    for (int kk = 0; kk < 2; ++kk)
#pragma unroll
      for (int mi = 0; mi < 4; ++mi)
#pragma unroll
        for (int ni = 0; ni < 4; ++ni)
          acc[mi][ni] = __builtin_amdgcn_mfma_f32_16x16x32_bf16(fa[kk][mi], fb[kk][ni], acc[mi][ni], 0, 0, 0);
    if (kt + 1 < nk) {
      asm volatile("s_waitcnt vmcnt(0)" ::: "memory");
      write_lds(cur ^ 1);                  // MFMAs (non-mem) schedule around this
    }
    cur ^= 1;
  }

  float* dst = (EPI == 3) ? (Cf + (size_t)blockIdx.z * M * N) : Cf;
#pragma unroll
  for (int mi = 0; mi < 4; ++mi) {
#pragma unroll
    for (int ni = 0; ni < 4; ++ni) {
      int colb = col0 + wn * 64 + ni * 16 + l15;
      float bv = (EPI == 3) ? 0.f : bias[colb];
#pragma unroll
      for (int r = 0; r < 4; ++r) {
        int rowb = row0 + wm * 64 + mi * 16 + hi * 4 + r;
        float v = acc[mi][ni][r] + bv;
        if (EPI == 1) v = fmaxf(v, 0.f);
        if (EPI == 3) {
          dst[(size_t)rowb * N + colb] = v;
        } else {
          Cb[(size_t)rowb * N + colb] = f2bf(v);
        }
      }
    }
  }
}

// ---------------- per-span attention ----------------
// KV: 4096 x 1536 bf16 rows (K | V). ctx out: 2048 x 768 bf16.
__global__ __launch_bounds__(384) void attn_kernel(const short* __restrict__ KV,
                                                   const int* __restrict__ sid,
                                                   const float* __restrict__ qs,
                                                   short* __restrict__ ctx) {
  int n = blockIdx.x;
  int b = n >> 8;                       // NS=256
  __shared__ int posO[Ww];
  __shared__ float attnL[NHh][Ww];
  __shared__ int lenS;
  int tid = threadIdx.x;
  if (tid < Ww) {
    int st = sid[2 * n], en = sid[2 * n + 1];
    int p = st + tid;
    p = p < 0 ? 0 : (p > SLh - 1 ? SLh - 1 : p);
    posO[tid] = (b * SLh + p) * (2 * Hh);
    if (tid == 0) lenS = en - st;
  }
  __syncthreads();
  int len = lenS;
  int h = tid >> 5, w = tid & 31;       // 12*32 = 384
  const int4* kr = (const int4*)(KV + posO[w] + h * HDd);
  const float4* qp = (const float4*)(qs + h * HDd);
  float acc = 0.f;
#pragma unroll
  for (int j = 0; j < 8; ++j) {
    int4 kk = kr[j];
    float4 qa = qp[2 * j], qb = qp[2 * j + 1];
    acc += qa.x * bflo(kk.x) + qa.y * bfhi(kk.x) + qa.z * bflo(kk.y) + qa.w * bfhi(kk.y);
    acc += qb.x * bflo(kk.z) + qb.y * bfhi(kk.z) + qb.z * bflo(kk.w) + qb.w * bfhi(kk.w);
  }
  float score = (w < len) ? acc : -1e9f;
  float m = score;
#pragma unroll
  for (int o = 16; o; o >>= 1) m = fmaxf(m, __shfl_xor(m, o, 32));
  float e = __expf(score - m);
  float ssum = e;
#pragma unroll
  for (int o = 16; o; o >>= 1) ssum += __shfl_xor(ssum, o, 32);
  attnL[h][w] = e / ssum;
  __syncthreads();
  int hh = tid >> 5, dp = tid & 31;
  float a0 = 0.f, a1 = 0.f;
#pragma unroll
  for (int w2 = 0; w2 < Ww; ++w2) {
    float aw = attnL[hh][w2];
    unsigned u = *(const unsigned*)(KV + posO[w2] + Hh + hh * HDd + 2 * dp);
    a0 += aw * bflo(u);
    a1 += aw * bfhi(u);
  }
  unsigned packed = (unsigned)(unsigned short)f2bf(a0) | ((unsigned)(unsigned short)f2bf(a1) << 16);
  ((unsigned*)ctx)[(size_t)n * (Hh / 2) + tid] = packed;
}

// ---------------- LN over (Ya+Yb+bias2), out f32 + bf16 ----------------
__global__ __launch_bounds__(256) void ln_kernel(const float* __restrict__ Ya,
                                                 const float* __restrict__ Yb,
                                                 const float* __restrict__ bias2,
                                                 const float* __restrict__ g,
                                                 const float* __restrict__ b,
                                                 float* __restrict__ xf,
                                                 short* __restrict__ xb) {
  int row = blockIdx.x;
  int tid = threadIdx.x;
  float v[3]; float s1 = 0.f, s2 = 0.f;
#pragma unroll
  for (int i = 0; i < 3; ++i) {
    int c = tid + 256 * i;
    size_t idx = (size_t)row * Hh + c;
    v[i] = Ya[idx] + Yb[idx] + bias2[c];
    s1 += v[i]; s2 += v[i] * v[i];
  }
  __shared__ float r1[4], r2[4];
#pragma unroll
  for (int o = 32; o; o >>= 1) { s1 += __shfl_xor(s1, o); s2 += __shfl_xor(s2, o); }
  int lane = tid & 63, wv = tid >> 6;
  if (lane == 0) { r1[wv] = s1; r2[wv] = s2; }
  __syncthreads();
  s1 = r1[0] + r1[1] + r1[2] + r1[3];
  s2 = r2[0] + r2[1] + r2[2] + r2[3];
  float mu = s1 * (1.f / Hh);
  float var = s2 * (1.f / Hh) - mu * mu;
  float is = rsqrtf(var + 1e-5f);
#pragma unroll
  for (int i = 0; i < 3; ++i) {
    int c = tid + 256 * i;
    float o = (v[i] - mu) * is * g[c] + b[c];
    xf[(size_t)row * Hh + c] = o;
    xb[(size_t)row * Hh + c] = f2bf(o);
  }
}

// ---------------- final LN over (sum of 4 partials + b2 + x) + mask ----------------
__global__ __launch_bounds__(256) void ln_final(const float* __restrict__ Y4,
                                                const float* __restrict__ b2,
                                                const float* __restrict__ xf,
                                                const float* __restrict__ g,
                                                const float* __restrict__ b,
                                                const int* __restrict__ sid,
                                                float* __restrict__ out) {
  const size_t SL4 = (size_t)NSPAN * Hh;
  int row = blockIdx.x;
  int len = sid[2 * row + 1] - sid[2 * row];
  int tid = threadIdx.x;
  float v[3]; float s1 = 0.f, s2 = 0.f;
#pragma unroll
  for (int i = 0; i < 3; ++i) {
    int c = tid + 256 * i;
    size_t idx = (size_t)row * Hh + c;
    v[i] = Y4[idx] + Y4[idx + SL4] + Y4[idx + 2 * SL4] + Y4[idx + 3 * SL4]
         + b2[c] + xf[idx];
    s1 += v[i]; s2 += v[i] * v[i];
  }
  __shared__ float r1[4], r2[4];
#pragma unroll
  for (int o = 32; o; o >>= 1) { s1 += __shfl_xor(s1, o); s2 += __shfl_xor(s2, o); }
  int lane = tid & 63, wv = tid >> 6;
  if (lane == 0) { r1[wv] = s1; r2[wv] = s2; }
  __syncthreads();
  s1 = r1[0] + r1[1] + r1[2] + r1[3];
  s2 = r2[0] + r2[1] + r2[2] + r2[3];
  float mu = s1 * (1.f / Hh);
  float var = s2 * (1.f / Hh) - mu * mu;
  float is = rsqrtf(var + 1e-5f);
  float keep = (len > 0) ? 1.f : 0.f;
#pragma unroll
  for (int i = 0; i < 3; ++i) {
    int c = tid + 256 * i;
    float o = ((v[i] - mu) * is * g[c] + b[c]) * keep;
    out[(size_t)row * Hh + c] = o;
  }
}

extern "C" void kernel_launch(void* const* d_in, const int* in_sizes, int n_in,
                              void* d_out, int out_size, void* d_ws, size_t ws_size,
                              hipStream_t stream) {
  const float* token_reps = (const float*)d_in[0];
  const int* span_ids = (const int*)d_in[1];
  const float* dq = (const float*)d_in[2];
  const float* ipw = (const float*)d_in[3];
  const float* ipb = (const float*)d_in[4];
  const float* opw = (const float*)d_in[5];
  const float* opb = (const float*)d_in[6];
  const float* lng = (const float*)d_in[7];
  const float* lnb = (const float*)d_in[8];
  const float* w1 = (const float*)d_in[9];
  const float* b1 = (const float*)d_in[10];
  const float* w2 = (const float*)d_in[11];
  const float* b2 = (const float*)d_in[12];
  float* out = (float*)d_out;

  char* p = (char*)d_ws;
  auto alloc = [&](size_t bytes) { void* r = p; p += (bytes + 255) & ~(size_t)255; return r; };
  short* tokb = (short*)alloc((size_t)NTOK * Hh * 2);
  short* kvw  = (short*)alloc((size_t)2 * Hh * Hh * 2);
  short* outw = (short*)alloc((size_t)Hh * Hh * 2);
  short* w1b  = (short*)alloc((size_t)FFN_I * Hh * 2);
  short* w2b  = (short*)alloc((size_t)Hh * FFN_I * 2);
  float* qsv  = (float*)alloc(Hh * 4);
  float* bias2= (float*)alloc(Hh * 4);
  short* KV   = (short*)alloc((size_t)NTOK * 2 * Hh * 2);
  short* ctxb = (short*)alloc((size_t)NSPAN * Hh * 2);
  float* attnY= (float*)alloc((size_t)2 * NSPAN * Hh * 4);  // outproj partials x2
  float* xf   = (float*)alloc((size_t)NSPAN * Hh * 4);
  short* xb   = (short*)alloc((size_t)NSPAN * Hh * 2);
  short* hb   = (short*)alloc((size_t)NSPAN * FFN_I * 2);
  float* y2   = (float*)alloc((size_t)4 * NSPAN * Hh * 4);  // FFN2 partials x4

  // 1. tok = token_reps + pe  (bf16)
  tok_kernel<<<NTOK, 192, 0, stream>>>(token_reps, tokb);
  // 2. fused weight casts
  cast4<<<6336, 256, 0, stream>>>(ipw + (size_t)Hh * Hh, opw, w1, w2,
                                  kvw, outw, w1b, w2b);
  // 3. q vector + combined bias
  prep_qb<<<12, 64, 0, stream>>>(dq, ipw, ipb, opb, qsv, bias2);
  // 4. KV = tok @ [Wk;Wv]^T + [bk;bv]   (4096 x 1536 bf16)
  gemm_bt<0><<<dim3(12, 32, 1), 256, 0, stream>>>(tokb, kvw, ipb + Hh,
                                                  nullptr, KV,
                                                  NTOK, 2 * Hh, Hh, Hh);
  // 5. per-span attention -> ctx
  attn_kernel<<<NSPAN, 384, 0, stream>>>(KV, span_ids, qsv, ctxb);
  // 6. attn_out partials = ctx @ Wo^T  (split-K=2 -> attnY slices)
  gemm_bt<3><<<dim3(6, 16, 2), 256, 0, stream>>>(ctxb, outw, nullptr,
                                                 attnY, nullptr,
                                                 NSPAN, Hh, Hh, Hh / 2);
  // 7. x = LN(attnY0 + attnY1 + (bo + q0))
  ln_kernel<<<NSPAN, 256, 0, stream>>>(attnY, attnY + (size_t)NSPAN * Hh,
                                       bias2, lng, lnb, xf, xb);
  // 8. h = relu(x @ W1^T + b1)  (bf16)
  gemm_bt<1><<<dim3(24, 16, 1), 256, 0, stream>>>(xb, w1b, b1,
                                                  nullptr, hb,
                                                  NSPAN, FFN_I, Hh, Hh);
  // 9. y2 partials = h @ W2^T  (split-K=4 -> y2 slices)
  gemm_bt<3><<<dim3(6, 16, 4), 256, 0, stream>>>(hb, w2b, nullptr,
                                                 y2, nullptr,
                                                 NSPAN, Hh, FFN_I, FFN_I / 4);
  // 10. out = LN(sum(y2) + b2 + x) masked by len>0
  ln_final<<<NSPAN, 256, 0, stream>>>(y2, b2, xf, lng, lnb, span_ids, out);
}

// Round 6
// 234.768 us; speedup vs baseline: 1.7360x; 1.7360x over previous
//
#include <hip/hip_runtime.h>
#include <hip/hip_bf16.h>
#include <cstdint>

// Problem constants
#define Bb 8
#define SLh 512
#define Hh 768
#define NSs 256
#define Ww 32
#define NHh 12
#define HDd 64
#define FFN_I 3072
#define NTOK (Bb*SLh)      // 4096
#define NSPAN (Bb*NSs)     // 2048

typedef __attribute__((ext_vector_type(8))) __bf16 bf16x8;
typedef __attribute__((ext_vector_type(4))) float f32x4;

__device__ __forceinline__ short f2bf(float f) {
  unsigned u = __builtin_bit_cast(unsigned, f);
  unsigned r = (u + 0x7fffu + ((u >> 16) & 1u)) >> 16;
  return (short)r;
}
__device__ __forceinline__ float bflo(unsigned u) { return __builtin_bit_cast(float, u << 16); }
__device__ __forceinline__ float bfhi(unsigned u) { return __builtin_bit_cast(float, u & 0xffff0000u); }

__device__ __forceinline__ void gload16(const void* g, void* l) {
  __builtin_amdgcn_global_load_lds(
      (__attribute__((address_space(1))) void*)(const_cast<void*>(g)),
      (__attribute__((address_space(3))) void*)l, 16, 0, 0);
}

// ---------------- tok = token_reps + pos_encoding, cast bf16 ----------------
__global__ __launch_bounds__(192) void tok_kernel(const float* __restrict__ tr,
                                                  short* __restrict__ tok) {
  int row = blockIdx.x;            // 4096 = b*512+s
  int s = row & (SLh - 1);
  int c0 = threadIdx.x * 4;        // 192 threads * 4 = 768
  float4 v = *(const float4*)(tr + (size_t)row * Hh + c0);
  const float kinv = -9.210340371976184f / (float)Hh;  // -ln(10000)/H
  float f0 = __expf((float)c0 * kinv);
  float f1 = __expf((float)(c0 + 2) * kinv);
  float s0, cc0, s1, cc1;
  __sincosf((float)s * f0, &s0, &cc0);
  __sincosf((float)s * f1, &s1, &cc1);
  v.x += s0; v.y += cc0; v.z += s1; v.w += cc1;
  short4 o{f2bf(v.x), f2bf(v.y), f2bf(v.z), f2bf(v.w)};
  *(short4*)(tok + (size_t)row * Hh + c0) = o;
}

// ---------------- fused f32 -> bf16 cast of the 4 weight matrices ----------------
__global__ __launch_bounds__(256) void cast4(const float* __restrict__ s0,
                                             const float* __restrict__ s1,
                                             const float* __restrict__ s2,
                                             const float* __restrict__ s3,
                                             short* __restrict__ d0,
                                             short* __restrict__ d1,
                                             short* __restrict__ d2,
                                             short* __restrict__ d3) {
  int b = blockIdx.x;
  const float* s; short* d; int off;
  if (b < 1152)      { s = s0; d = d0; off = b; }
  else if (b < 1728) { s = s1; d = d1; off = b - 1152; }
  else if (b < 4032) { s = s2; d = d2; off = b - 1728; }
  else               { s = s3; d = d3; off = b - 4032; }
  int i = off * 256 + threadIdx.x;
  float4 v = ((const float4*)s)[i];
  short4 o{f2bf(v.x), f2bf(v.y), f2bf(v.z), f2bf(v.w)};
  ((short4*)d)[i] = o;
}

// ---------------- q vector (scaled 1/8) and bias2 = out_proj_b + q0 ----------------
__global__ __launch_bounds__(64) void prep_qb(const float* __restrict__ dq,
                                              const float* __restrict__ ipw,
                                              const float* __restrict__ ipb,
                                              const float* __restrict__ opb,
                                              float* __restrict__ qsv,
                                              float* __restrict__ bias2) {
  int h = blockIdx.x * 64 + threadIdx.x;   // 12 blocks * 64 = 768
  const float4* wr = (const float4*)(ipw + (size_t)h * Hh);  // Wq rows 0..767
  const float4* qv = (const float4*)dq;
  float acc = 0.f;
  for (int j = 0; j < Hh / 4; ++j) {
    float4 w4 = wr[j], q4 = qv[j];
    acc += w4.x * q4.x + w4.y * q4.y + w4.z * q4.z + w4.w * q4.w;
  }
  acc += ipb[h];
  qsv[h] = acc * 0.125f;          // / sqrt(64)
  bias2[h] = opb[h] + dq[h];
}

// ---------------- bf16 MFMA GEMM, C = A(MxK) * Bt(NxK)^T ----------------
// 128x64 tile, BK=64, 256 threads (4 waves 2Mx2N -> 64x32 per wave, 4x2 acc).
// DMA staging (global_load_lds w16) with XOR-swizzled SOURCE column (LDS dest
// linear) + matching swizzled ds_read (rule #21 / R2-proven pattern).
// Double-buffered 48 KB LDS -> 3 blocks/CU; raw s_barrier + counted vmcnt(6).
// All grids sized to 768 blocks = 3 blocks/CU for latency hiding.
// EPI 0: bf16 = acc+bias ; 1: bf16 = relu(acc+bias) ;
// EPI 3: f32 partial = acc into Cf + blockIdx.z*M*N (split-K).
template <int EPI>
__global__ __launch_bounds__(256, 3) void gemm_bt(const short* __restrict__ A,
                                                  const short* __restrict__ Bt,
                                                  const float* __restrict__ bias,
                                                  float* __restrict__ Cf,
                                                  short* __restrict__ Cb,
                                                  int M, int N, int ldk, int Kc) {
  __shared__ __align__(16) char Al[2][128 * 128];  // 128 rows x 128 B (16 KB/buf)
  __shared__ __align__(16) char Bl[2][64 * 128];   //  64 rows x 128 B ( 8 KB/buf)
  const int tid = threadIdx.x;
  const int lane = tid & 63, wave = tid >> 6;
  const int wm = wave >> 1, wn = wave & 1;         // 2x2 wave grid
  const int row0 = blockIdx.y * 128, col0 = blockIdx.x * 64;
  const int kbase = blockIdx.z * Kc;
  const int l15 = lane & 15, hi = lane >> 4;
  f32x4 acc[4][2] = {};
  const int nk = Kc >> 6;
  const int srow = tid >> 3, sslot = tid & 7;      // c=j*256+tid: row=j*32+srow, slot=sslot

  // Stage K-tile kt into buffer bi. LDS chunk c=(row*8+slot) is linear (DMA);
  // slot sd of row r is fed from global col-chunk sd^(r&7)  (inverse==forward).
  auto stage = [&](int kt, int bi) {
    const short* Agp = A + (size_t)row0 * ldk + kbase + kt * 64;
    const short* Bgp = Bt + (size_t)col0 * ldk + kbase + kt * 64;
#pragma unroll
    for (int j = 0; j < 4; ++j) {                  // A: 1024 chunks
      int row = j * 32 + srow;
      int col = (sslot ^ (row & 7)) << 3;
      gload16(Agp + (size_t)row * ldk + col,
              &Al[bi][0] + (size_t)(j * 256 + wave * 64) * 16);
    }
#pragma unroll
    for (int j = 0; j < 2; ++j) {                  // B: 512 chunks
      int row = j * 32 + srow;
      int col = (sslot ^ (row & 7)) << 3;
      gload16(Bgp + (size_t)row * ldk + col,
              &Bl[bi][0] + (size_t)(j * 256 + wave * 64) * 16);
    }
  };

  stage(0, 0);                                     // 6 loads/lane in flight
  for (int kt = 0; kt < nk; ++kt) {
    const int cur = kt & 1;
    if (kt + 1 < nk) {
      stage(kt + 1, cur ^ 1);                      // prefetch next tile (+6)
      asm volatile("s_waitcnt vmcnt(6)" ::: "memory");  // stage(kt) landed
    } else {
      asm volatile("s_waitcnt vmcnt(0)" ::: "memory");
    }
    __builtin_amdgcn_s_barrier();                  // buf cur ready everywhere
    asm volatile("" ::: "memory");
    bf16x8 fa[2][4], fb[2][2];
#pragma unroll
    for (int kk = 0; kk < 2; ++kk) {
#pragma unroll
      for (int i = 0; i < 4; ++i) {
        int Ra = wm * 64 + i * 16 + l15;
        fa[kk][i] = *(const bf16x8*)(&Al[cur][0] + (size_t)Ra * 128 +
                                     (((kk * 4 + hi) ^ (Ra & 7)) << 4));
      }
#pragma unroll
      for (int i = 0; i < 2; ++i) {
        int Rb = wn * 32 + i * 16 + l15;
        fb[kk][i] = *(const bf16x8*)(&Bl[cur][0] + (size_t)Rb * 128 +
                                     (((kk * 4 + hi) ^ (Rb & 7)) << 4));
      }
    }
#pragma unroll
    for (int kk = 0; kk < 2; ++kk)
#pragma unroll
      for (int mi = 0; mi < 4; ++mi)
#pragma unroll
        for (int ni = 0; ni < 2; ++ni)
          acc[mi][ni] = __builtin_amdgcn_mfma_f32_16x16x32_bf16(fa[kk][mi], fb[kk][ni], acc[mi][ni], 0, 0, 0);
    asm volatile("" ::: "memory");
    __builtin_amdgcn_s_barrier();                  // reads of cur done
  }

  float* dst = (EPI == 3) ? (Cf + (size_t)blockIdx.z * M * N) : Cf;
#pragma unroll
  for (int mi = 0; mi < 4; ++mi) {
#pragma unroll
    for (int ni = 0; ni < 2; ++ni) {
      int colb = col0 + wn * 32 + ni * 16 + l15;
      float bv = (EPI == 3) ? 0.f : bias[colb];
#pragma unroll
      for (int r = 0; r < 4; ++r) {
        int rowb = row0 + wm * 64 + mi * 16 + hi * 4 + r;
        float v = acc[mi][ni][r] + bv;
        if (EPI == 1) v = fmaxf(v, 0.f);
        if (EPI == 3) {
          dst[(size_t)rowb * N + colb] = v;
        } else {
          Cb[(size_t)rowb * N + colb] = f2bf(v);
        }
      }
    }
  }
}

// ---------------- per-span attention ----------------
// KV: 4096 x 1536 bf16 rows (K | V). ctx out: 2048 x 768 bf16.
__global__ __launch_bounds__(384) void attn_kernel(const short* __restrict__ KV,
                                                   const int* __restrict__ sid,
                                                   const float* __restrict__ qs,
                                                   short* __restrict__ ctx) {
  int n = blockIdx.x;
  int b = n >> 8;                       // NS=256
  __shared__ int posO[Ww];
  __shared__ float attnL[NHh][Ww];
  __shared__ int lenS;
  int tid = threadIdx.x;
  if (tid < Ww) {
    int st = sid[2 * n], en = sid[2 * n + 1];
    int p = st + tid;
    p = p < 0 ? 0 : (p > SLh - 1 ? SLh - 1 : p);
    posO[tid] = (b * SLh + p) * (2 * Hh);
    if (tid == 0) lenS = en - st;
  }
  __syncthreads();
  int len = lenS;
  int h = tid >> 5, w = tid & 31;       // 12*32 = 384
  const int4* kr = (const int4*)(KV + posO[w] + h * HDd);
  const float4* qp = (const float4*)(qs + h * HDd);
  float acc = 0.f;
#pragma unroll
  for (int j = 0; j < 8; ++j) {
    int4 kk = kr[j];
    float4 qa = qp[2 * j], qb = qp[2 * j + 1];
    acc += qa.x * bflo(kk.x) + qa.y * bfhi(kk.x) + qa.z * bflo(kk.y) + qa.w * bfhi(kk.y);
    acc += qb.x * bflo(kk.z) + qb.y * bfhi(kk.z) + qb.z * bflo(kk.w) + qb.w * bfhi(kk.w);
  }
  float score = (w < len) ? acc : -1e9f;
  float m = score;
#pragma unroll
  for (int o = 16; o; o >>= 1) m = fmaxf(m, __shfl_xor(m, o, 32));
  float e = __expf(score - m);
  float ssum = e;
#pragma unroll
  for (int o = 16; o; o >>= 1) ssum += __shfl_xor(ssum, o, 32);
  attnL[h][w] = e / ssum;
  __syncthreads();
  int hh = tid >> 5, dp = tid & 31;
  float a0 = 0.f, a1 = 0.f;
#pragma unroll
  for (int w2 = 0; w2 < Ww; ++w2) {
    float aw = attnL[hh][w2];
    unsigned u = *(const unsigned*)(KV + posO[w2] + Hh + hh * HDd + 2 * dp);
    a0 += aw * bflo(u);
    a1 += aw * bfhi(u);
  }
  unsigned packed = (unsigned)(unsigned short)f2bf(a0) | ((unsigned)(unsigned short)f2bf(a1) << 16);
  ((unsigned*)ctx)[(size_t)n * (Hh / 2) + tid] = packed;
}

// ---------------- LN over (4 partials + bias2), out f32 + bf16 ----------------
__global__ __launch_bounds__(256) void ln_kernel(const float* __restrict__ Y4,
                                                 const float* __restrict__ bias2,
                                                 const float* __restrict__ g,
                                                 const float* __restrict__ b,
                                                 float* __restrict__ xf,
                                                 short* __restrict__ xb) {
  const size_t SL = (size_t)NSPAN * Hh;
  int row = blockIdx.x;
  int tid = threadIdx.x;
  float v[3]; float s1 = 0.f, s2 = 0.f;
#pragma unroll
  for (int i = 0; i < 3; ++i) {
    int c = tid + 256 * i;
    size_t idx = (size_t)row * Hh + c;
    v[i] = Y4[idx] + Y4[idx + SL] + Y4[idx + 2 * SL] + Y4[idx + 3 * SL] + bias2[c];
    s1 += v[i]; s2 += v[i] * v[i];
  }
  __shared__ float r1[4], r2[4];
#pragma unroll
  for (int o = 32; o; o >>= 1) { s1 += __shfl_xor(s1, o); s2 += __shfl_xor(s2, o); }
  int lane = tid & 63, wv = tid >> 6;
  if (lane == 0) { r1[wv] = s1; r2[wv] = s2; }
  __syncthreads();
  s1 = r1[0] + r1[1] + r1[2] + r1[3];
  s2 = r2[0] + r2[1] + r2[2] + r2[3];
  float mu = s1 * (1.f / Hh);
  float var = s2 * (1.f / Hh) - mu * mu;
  float is = rsqrtf(var + 1e-5f);
#pragma unroll
  for (int i = 0; i < 3; ++i) {
    int c = tid + 256 * i;
    float o = (v[i] - mu) * is * g[c] + b[c];
    xf[(size_t)row * Hh + c] = o;
    xb[(size_t)row * Hh + c] = f2bf(o);
  }
}

// ---------------- final LN over (4 partials + b2 + x) + mask ----------------
__global__ __launch_bounds__(256) void ln_final(const float* __restrict__ Y4,
                                                const float* __restrict__ b2,
                                                const float* __restrict__ xf,
                                                const float* __restrict__ g,
                                                const float* __restrict__ b,
                                                const int* __restrict__ sid,
                                                float* __restrict__ out) {
  const size_t SL = (size_t)NSPAN * Hh;
  int row = blockIdx.x;
  int len = sid[2 * row + 1] - sid[2 * row];
  int tid = threadIdx.x;
  float v[3]; float s1 = 0.f, s2 = 0.f;
#pragma unroll
  for (int i = 0; i < 3; ++i) {
    int c = tid + 256 * i;
    size_t idx = (size_t)row * Hh + c;
    v[i] = Y4[idx] + Y4[idx + SL] + Y4[idx + 2 * SL] + Y4[idx + 3 * SL]
         + b2[c] + xf[idx];
    s1 += v[i]; s2 += v[i] * v[i];
  }
  __shared__ float r1[4], r2[4];
#pragma unroll
  for (int o = 32; o; o >>= 1) { s1 += __shfl_xor(s1, o); s2 += __shfl_xor(s2, o); }
  int lane = tid & 63, wv = tid >> 6;
  if (lane == 0) { r1[wv] = s1; r2[wv] = s2; }
  __syncthreads();
  s1 = r1[0] + r1[1] + r1[2] + r1[3];
  s2 = r2[0] + r2[1] + r2[2] + r2[3];
  float mu = s1 * (1.f / Hh);
  float var = s2 * (1.f / Hh) - mu * mu;
  float is = rsqrtf(var + 1e-5f);
  float keep = (len > 0) ? 1.f : 0.f;
#pragma unroll
  for (int i = 0; i < 3; ++i) {
    int c = tid + 256 * i;
    float o = ((v[i] - mu) * is * g[c] + b[c]) * keep;
    out[(size_t)row * Hh + c] = o;
  }
}

extern "C" void kernel_launch(void* const* d_in, const int* in_sizes, int n_in,
                              void* d_out, int out_size, void* d_ws, size_t ws_size,
                              hipStream_t stream) {
  const float* token_reps = (const float*)d_in[0];
  const int* span_ids = (const int*)d_in[1];
  const float* dq = (const float*)d_in[2];
  const float* ipw = (const float*)d_in[3];
  const float* ipb = (const float*)d_in[4];
  const float* opw = (const float*)d_in[5];
  const float* opb = (const float*)d_in[6];
  const float* lng = (const float*)d_in[7];
  const float* lnb = (const float*)d_in[8];
  const float* w1 = (const float*)d_in[9];
  const float* b1 = (const float*)d_in[10];
  const float* w2 = (const float*)d_in[11];
  const float* b2 = (const float*)d_in[12];
  float* out = (float*)d_out;

  char* p = (char*)d_ws;
  auto alloc = [&](size_t bytes) { void* r = p; p += (bytes + 255) & ~(size_t)255; return r; };
  short* tokb = (short*)alloc((size_t)NTOK * Hh * 2);
  short* kvw  = (short*)alloc((size_t)2 * Hh * Hh * 2);
  short* outw = (short*)alloc((size_t)Hh * Hh * 2);
  short* w1b  = (short*)alloc((size_t)FFN_I * Hh * 2);
  short* w2b  = (short*)alloc((size_t)Hh * FFN_I * 2);
  float* qsv  = (float*)alloc(Hh * 4);
  float* bias2= (float*)alloc(Hh * 4);
  short* KV   = (short*)alloc((size_t)NTOK * 2 * Hh * 2);
  short* ctxb = (short*)alloc((size_t)NSPAN * Hh * 2);
  float* attnY= (float*)alloc((size_t)4 * NSPAN * Hh * 4);  // outproj partials x4
  float* xf   = (float*)alloc((size_t)NSPAN * Hh * 4);
  short* xb   = (short*)alloc((size_t)NSPAN * Hh * 2);
  short* hb   = (short*)alloc((size_t)NSPAN * FFN_I * 2);
  float* y2   = (float*)alloc((size_t)4 * NSPAN * Hh * 4);  // FFN2 partials x4

  // 1. tok = token_reps + pe  (bf16)
  tok_kernel<<<NTOK, 192, 0, stream>>>(token_reps, tokb);
  // 2. fused weight casts
  cast4<<<6336, 256, 0, stream>>>(ipw + (size_t)Hh * Hh, opw, w1, w2,
                                  kvw, outw, w1b, w2b);
  // 3. q vector + combined bias
  prep_qb<<<12, 64, 0, stream>>>(dq, ipw, ipb, opb, qsv, bias2);
  // 4. KV = tok @ [Wk;Wv]^T + [bk;bv]   (4096 x 1536 bf16) — 768 blocks
  gemm_bt<0><<<dim3(24, 32, 1), 256, 0, stream>>>(tokb, kvw, ipb + Hh,
                                                  nullptr, KV,
                                                  NTOK, 2 * Hh, Hh, Hh);
  // 5. per-span attention -> ctx
  attn_kernel<<<NSPAN, 384, 0, stream>>>(KV, span_ids, qsv, ctxb);
  // 6. attn_out partials = ctx @ Wo^T  (split-K=4 -> attnY slices) — 768 blocks
  gemm_bt<3><<<dim3(12, 16, 4), 256, 0, stream>>>(ctxb, outw, nullptr,
                                                  attnY, nullptr,
                                                  NSPAN, Hh, Hh, Hh / 4);
  // 7. x = LN(sum attnY + (bo + q0))
  ln_kernel<<<NSPAN, 256, 0, stream>>>(attnY, bias2, lng, lnb, xf, xb);
  // 8. h = relu(x @ W1^T + b1)  (bf16) — 768 blocks
  gemm_bt<1><<<dim3(48, 16, 1), 256, 0, stream>>>(xb, w1b, b1,
                                                  nullptr, hb,
                                                  NSPAN, FFN_I, Hh, Hh);
  // 9. y2 partials = h @ W2^T  (split-K=4 -> y2 slices) — 768 blocks
  gemm_bt<3><<<dim3(12, 16, 4), 256, 0, stream>>>(hb, w2b, nullptr,
                                                  y2, nullptr,
                                                  NSPAN, Hh, FFN_I, FFN_I / 4);
  // 10. out = LN(sum y2 + b2 + x) masked by len>0
  ln_final<<<NSPAN, 256, 0, stream>>>(y2, b2, xf, lng, lnb, span_ids, out);
}

// Round 7
// 210.305 us; speedup vs baseline: 1.9380x; 1.1163x over previous
//
#include <hip/hip_runtime.h>
#include <hip/hip_bf16.h>
#include <cstdint>

// Problem constants
#define Bb 8
#define SLh 512
#define Hh 768
#define NSs 256
#define Ww 32
#define NHh 12
#define HDd 64
#define FFN_I 3072
#define NTOK (Bb*SLh)      // 4096
#define NSPAN (Bb*NSs)     // 2048
#define NVS 832            // V cols (768) + 12 score cols + pad to 13*64

typedef __attribute__((ext_vector_type(8))) __bf16 bf16x8;
typedef __attribute__((ext_vector_type(4))) float f32x4;

__device__ __forceinline__ short f2bf(float f) {
  unsigned u = __builtin_bit_cast(unsigned, f);
  unsigned r = (u + 0x7fffu + ((u >> 16) & 1u)) >> 16;
  return (short)r;
}
__device__ __forceinline__ float bflo(unsigned u) { return __builtin_bit_cast(float, u << 16); }
__device__ __forceinline__ float bfhi(unsigned u) { return __builtin_bit_cast(float, u & 0xffff0000u); }

__device__ __forceinline__ void gload16(const void* g, void* l) {
  __builtin_amdgcn_global_load_lds(
      (__attribute__((address_space(1))) void*)(const_cast<void*>(g)),
      (__attribute__((address_space(3))) void*)l, 16, 0, 0);
}

// ---------------- tok = token_reps + pos_encoding, cast bf16 ----------------
__global__ __launch_bounds__(192) void tok_kernel(const float* __restrict__ tr,
                                                  short* __restrict__ tok) {
  int row = blockIdx.x;            // 4096 = b*512+s
  int s = row & (SLh - 1);
  int c0 = threadIdx.x * 4;        // 192 threads * 4 = 768
  float4 v = *(const float4*)(tr + (size_t)row * Hh + c0);
  const float kinv = -9.210340371976184f / (float)Hh;  // -ln(10000)/H
  float f0 = __expf((float)c0 * kinv);
  float f1 = __expf((float)(c0 + 2) * kinv);
  float s0, cc0, s1, cc1;
  __sincosf((float)s * f0, &s0, &cc0);
  __sincosf((float)s * f1, &s1, &cc1);
  v.x += s0; v.y += cc0; v.z += s1; v.w += cc1;
  short4 o{f2bf(v.x), f2bf(v.y), f2bf(v.z), f2bf(v.w)};
  *(short4*)(tok + (size_t)row * Hh + c0) = o;
}

// ------- fused f32 -> bf16 cast: Wv, Wo, W1, W2 + zero-fill of vsw pad -------
// blocks: [0,576) Wv -> vsw rows 0..767 ; [576,1152) Wo ; [1152,3456) w1 ;
//         [3456,5760) w2 ; [5760,5799) zero vsw rows 780..831
__global__ __launch_bounds__(256) void cast4(const float* __restrict__ s0,
                                             const float* __restrict__ s1,
                                             const float* __restrict__ s2,
                                             const float* __restrict__ s3,
                                             short* __restrict__ d0,
                                             short* __restrict__ d1,
                                             short* __restrict__ d2,
                                             short* __restrict__ d3) {
  int b = blockIdx.x;
  if (b >= 5760) {                 // zero pad rows 780..831 of vsw
    int i = (b - 5760) * 256 + threadIdx.x;          // 9984 short4
    ((short4*)d0)[149760 + i] = short4{0, 0, 0, 0};  // 780*768/4 = 149760
    return;
  }
  const float* s; short* d; int off;
  if (b < 576)       { s = s0; d = d0; off = b; }
  else if (b < 1152) { s = s1; d = d1; off = b - 576; }
  else if (b < 3456) { s = s2; d = d2; off = b - 1152; }
  else               { s = s3; d = d3; off = b - 3456; }
  int i = off * 256 + threadIdx.x;
  float4 v = ((const float4*)s)[i];
  short4 o{f2bf(v.x), f2bf(v.y), f2bf(v.z), f2bf(v.w)};
  ((short4*)d)[i] = o;
}

// ---- qsv=(Wq q + bq)/8, bias2 = bo + q0, bvs = [bv | sb | 0] (score bias) ----
__global__ __launch_bounds__(64) void prep_qb(const float* __restrict__ dq,
                                              const float* __restrict__ ipw,
                                              const float* __restrict__ ipb,
                                              const float* __restrict__ opb,
                                              float* __restrict__ qsv,
                                              float* __restrict__ bias2,
                                              float* __restrict__ bvs) {
  int b = blockIdx.x, lane = threadIdx.x;
  if (b == 12) { if (lane < 52) bvs[780 + lane] = 0.f; return; }
  int h = b * 64 + lane;                       // 12 blocks * 64 = 768
  const float4* wr = (const float4*)(ipw + (size_t)h * Hh);   // Wq rows
  const float4* qv = (const float4*)dq;
  float acc = 0.f;
  for (int j = 0; j < Hh / 4; ++j) {
    float4 w4 = wr[j], q4 = qv[j];
    acc += w4.x * q4.x + w4.y * q4.y + w4.z * q4.z + w4.w * q4.w;
  }
  acc += ipb[h];
  float qs = acc * 0.125f;                     // / sqrt(64)
  qsv[h] = qs;
  bias2[h] = opb[h] + dq[h];
  bvs[h] = ipb[2 * Hh + h];                    // bv
  float t = qs * ipb[Hh + h];                  // qsv . bk  (head-local reduce)
#pragma unroll
  for (int o = 32; o; o >>= 1) t += __shfl_xor(t, o);
  if (lane == 0) bvs[768 + b] = t;             // sb[h]
}

// ---- qk[h] = Wk_h^T qsv_h, written as bf16 rows 768..779 of vsw ----
__global__ __launch_bounds__(64) void qk_kernel(const float* __restrict__ ipw,
                                                const float* __restrict__ qsv,
                                                short* __restrict__ vsw) {
  int h = blockIdx.x, dc = blockIdx.y, lane = threadIdx.x;
  int d = dc * 64 + lane;
  const float* wk = ipw + (size_t)(Hh + h * 64) * Hh + d;     // Wk rows
  const float* qh = qsv + h * 64;
  float a = 0.f;
#pragma unroll 8
  for (int e = 0; e < 64; ++e) a += qh[e] * wk[(size_t)e * Hh];
  vsw[(size_t)(768 + h) * Hh + d] = f2bf(a);
}

// ---------------- bf16 MFMA GEMM, C = A(MxK) * Bt(NxK)^T ----------------
// 128x64 tile, BK=64, 256 thr (4 waves 2Mx2N), DMA staging w/ XOR-swizzled
// source col (R2-proven, 0 bank conflicts), dbuf 48KB -> 3 blocks/CU,
// counted vmcnt(6). XCD-clustered remap (T1): xcd=bid&7 owns ypp row-panels
// so A-panels + B stay in the XCD's private L2.  z = blockIdx.y (split-K).
// EPI 1: bf16 = relu(acc+bias) ; 3: f32 partial -> Cf + z*M*N ;
// EPI 4: cols<768 -> V bf16 (stride 768); 768<=col<780 -> S f32 (stride 12).
template <int EPI>
__global__ __launch_bounds__(256, 3) void gemm_bt(const short* __restrict__ A,
                                                  const short* __restrict__ Bt,
                                                  const float* __restrict__ bias,
                                                  float* __restrict__ Cf,
                                                  short* __restrict__ Cb,
                                                  int M, int N, int ldk, int Kc,
                                                  int nx, int ypp) {
  __shared__ __align__(16) char Al[2][128 * 128];
  __shared__ __align__(16) char Bl[2][64 * 128];
  const int tid = threadIdx.x;
  const int lane = tid & 63, wave = tid >> 6;
  const int wm = wave >> 1, wn = wave & 1;
  const int bid = blockIdx.x, xcd = bid & 7, ii = bid >> 3;
  const int iy = ii / nx;
  const int by = xcd * ypp + iy, bx = ii - iy * nx;
  const int row0 = by * 128, col0 = bx * 64;
  const int kbase = blockIdx.y * Kc;
  const int l15 = lane & 15, hi = lane >> 4;
  f32x4 acc[4][2] = {};
  const int nk = Kc >> 6;
  const int srow = tid >> 3, sslot = tid & 7;

  auto stage = [&](int kt, int bi) {
    const short* Agp = A + (size_t)row0 * ldk + kbase + kt * 64;
    const short* Bgp = Bt + (size_t)col0 * ldk + kbase + kt * 64;
#pragma unroll
    for (int j = 0; j < 4; ++j) {
      int row = j * 32 + srow;
      int col = (sslot ^ (row & 7)) << 3;
      gload16(Agp + (size_t)row * ldk + col,
              &Al[bi][0] + (size_t)(j * 256 + wave * 64) * 16);
    }
#pragma unroll
    for (int j = 0; j < 2; ++j) {
      int row = j * 32 + srow;
      int col = (sslot ^ (row & 7)) << 3;
      gload16(Bgp + (size_t)row * ldk + col,
              &Bl[bi][0] + (size_t)(j * 256 + wave * 64) * 16);
    }
  };

  stage(0, 0);
  for (int kt = 0; kt < nk; ++kt) {
    const int cur = kt & 1;
    if (kt + 1 < nk) {
      stage(kt + 1, cur ^ 1);
      asm volatile("s_waitcnt vmcnt(6)" ::: "memory");
    } else {
      asm volatile("s_waitcnt vmcnt(0)" ::: "memory");
    }
    __builtin_amdgcn_s_barrier();
    asm volatile("" ::: "memory");
    bf16x8 fa[2][4], fb[2][2];
#pragma unroll
    for (int kk = 0; kk < 2; ++kk) {
#pragma unroll
      for (int i = 0; i < 4; ++i) {
        int Ra = wm * 64 + i * 16 + l15;
        fa[kk][i] = *(const bf16x8*)(&Al[cur][0] + (size_t)Ra * 128 +
                                     (((kk * 4 + hi) ^ (Ra & 7)) << 4));
      }
#pragma unroll
      for (int i = 0; i < 2; ++i) {
        int Rb = wn * 32 + i * 16 + l15;
        fb[kk][i] = *(const bf16x8*)(&Bl[cur][0] + (size_t)Rb * 128 +
                                     (((kk * 4 + hi) ^ (Rb & 7)) << 4));
      }
    }
#pragma unroll
    for (int kk = 0; kk < 2; ++kk)
#pragma unroll
      for (int mi = 0; mi < 4; ++mi)
#pragma unroll
        for (int ni = 0; ni < 2; ++ni)
          acc[mi][ni] = __builtin_amdgcn_mfma_f32_16x16x32_bf16(fa[kk][mi], fb[kk][ni], acc[mi][ni], 0, 0, 0);
    asm volatile("" ::: "memory");
    __builtin_amdgcn_s_barrier();
  }

  float* dst = (EPI == 3) ? (Cf + (size_t)blockIdx.y * M * N) : Cf;
#pragma unroll
  for (int mi = 0; mi < 4; ++mi) {
#pragma unroll
    for (int ni = 0; ni < 2; ++ni) {
      int colb = col0 + wn * 32 + ni * 16 + l15;
      float bv = (EPI == 3) ? 0.f : bias[colb];
#pragma unroll
      for (int r = 0; r < 4; ++r) {
        int rowb = row0 + wm * 64 + mi * 16 + hi * 4 + r;
        float v = acc[mi][ni][r] + bv;
        if (EPI == 1) {
          Cb[(size_t)rowb * N + colb] = f2bf(fmaxf(v, 0.f));
        } else if (EPI == 3) {
          dst[(size_t)rowb * N + colb] = v;
        } else {  // EPI 4: V | S split
          if (colb < 768) Cb[(size_t)rowb * 768 + colb] = f2bf(v);
          else if (colb < 780) Cf[(size_t)rowb * 12 + (colb - 768)] = v;
        }
      }
    }
  }
}

// ---------------- per-span attention (scores pre-computed in S) ----------------
// Vb: 4096 x 768 bf16. S: 4096 x 12 f32 (q.k/8 + sb). ctx: 2048 x 768 bf16.
__global__ __launch_bounds__(384) void attn_kernel(const short* __restrict__ Vb,
                                                   const float* __restrict__ S,
                                                   const int* __restrict__ sid,
                                                   short* __restrict__ ctx) {
  int n = blockIdx.x;
  int b = n >> 8;                       // NS=256
  __shared__ int posV[Ww], tS[Ww];
  __shared__ float attnL[NHh][Ww];
  __shared__ int lenS;
  int tid = threadIdx.x;
  if (tid < Ww) {
    int st = sid[2 * n], en = sid[2 * n + 1];
    int p = st + tid;
    p = p < 0 ? 0 : (p > SLh - 1 ? SLh - 1 : p);
    int t = b * SLh + p;
    posV[tid] = t * Hh;
    tS[tid] = t * 12;
    if (tid == 0) lenS = en - st;
  }
  __syncthreads();
  int len = lenS;
  int h = tid >> 5, w = tid & 31;       // 12*32 = 384
  float score = (w < len) ? S[tS[w] + h] : -1e9f;
  float m = score;
#pragma unroll
  for (int o = 16; o; o >>= 1) m = fmaxf(m, __shfl_xor(m, o, 32));
  float e = __expf(score - m);
  float ssum = e;
#pragma unroll
  for (int o = 16; o; o >>= 1) ssum += __shfl_xor(ssum, o, 32);
  attnL[h][w] = e / ssum;
  __syncthreads();
  int hh = tid >> 5, dp = tid & 31;
  float a0 = 0.f, a1 = 0.f;
#pragma unroll
  for (int w2 = 0; w2 < Ww; ++w2) {
    float aw = attnL[hh][w2];
    unsigned u = *(const unsigned*)(Vb + posV[w2] + hh * HDd + 2 * dp);
    a0 += aw * bflo(u);
    a1 += aw * bfhi(u);
  }
  unsigned packed = (unsigned)(unsigned short)f2bf(a0) | ((unsigned)(unsigned short)f2bf(a1) << 16);
  ((unsigned*)ctx)[(size_t)n * (Hh / 2) + tid] = packed;
}

// ---------------- LN over (2 partials + bias2), out f32 + bf16 ----------------
__global__ __launch_bounds__(256) void ln_kernel(const float* __restrict__ Y2,
                                                 const float* __restrict__ bias2,
                                                 const float* __restrict__ g,
                                                 const float* __restrict__ b,
                                                 float* __restrict__ xf,
                                                 short* __restrict__ xb) {
  const size_t SL = (size_t)NSPAN * Hh;
  int row = blockIdx.x;
  int tid = threadIdx.x;
  float v[3]; float s1 = 0.f, s2 = 0.f;
#pragma unroll
  for (int i = 0; i < 3; ++i) {
    int c = tid + 256 * i;
    size_t idx = (size_t)row * Hh + c;
    v[i] = Y2[idx] + Y2[idx + SL] + bias2[c];
    s1 += v[i]; s2 += v[i] * v[i];
  }
  __shared__ float r1[4], r2[4];
#pragma unroll
  for (int o = 32; o; o >>= 1) { s1 += __shfl_xor(s1, o); s2 += __shfl_xor(s2, o); }
  int lane = tid & 63, wv = tid >> 6;
  if (lane == 0) { r1[wv] = s1; r2[wv] = s2; }
  __syncthreads();
  s1 = r1[0] + r1[1] + r1[2] + r1[3];
  s2 = r2[0] + r2[1] + r2[2] + r2[3];
  float mu = s1 * (1.f / Hh);
  float var = s2 * (1.f / Hh) - mu * mu;
  float is = rsqrtf(var + 1e-5f);
#pragma unroll
  for (int i = 0; i < 3; ++i) {
    int c = tid + 256 * i;
    float o = (v[i] - mu) * is * g[c] + b[c];
    xf[(size_t)row * Hh + c] = o;
    xb[(size_t)row * Hh + c] = f2bf(o);
  }
}

// ---------------- final LN over (4 partials + b2 + x) + mask ----------------
__global__ __launch_bounds__(256) void ln_final(const float* __restrict__ Y4,
                                                const float* __restrict__ b2,
                                                const float* __restrict__ xf,
                                                const float* __restrict__ g,
                                                const float* __restrict__ b,
                                                const int* __restrict__ sid,
                                                float* __restrict__ out) {
  const size_t SL = (size_t)NSPAN * Hh;
  int row = blockIdx.x;
  int len = sid[2 * row + 1] - sid[2 * row];
  int tid = threadIdx.x;
  float v[3]; float s1 = 0.f, s2 = 0.f;
#pragma unroll
  for (int i = 0; i < 3; ++i) {
    int c = tid + 256 * i;
    size_t idx = (size_t)row * Hh + c;
    v[i] = Y4[idx] + Y4[idx + SL] + Y4[idx + 2 * SL] + Y4[idx + 3 * SL]
         + b2[c] + xf[idx];
    s1 += v[i]; s2 += v[i] * v[i];
  }
  __shared__ float r1[4], r2[4];
#pragma unroll
  for (int o = 32; o; o >>= 1) { s1 += __shfl_xor(s1, o); s2 += __shfl_xor(s2, o); }
  int lane = tid & 63, wv = tid >> 6;
  if (lane == 0) { r1[wv] = s1; r2[wv] = s2; }
  __syncthreads();
  s1 = r1[0] + r1[1] + r1[2] + r1[3];
  s2 = r2[0] + r2[1] + r2[2] + r2[3];
  float mu = s1 * (1.f / Hh);
  float var = s2 * (1.f / Hh) - mu * mu;
  float is = rsqrtf(var + 1e-5f);
  float keep = (len > 0) ? 1.f : 0.f;
#pragma unroll
  for (int i = 0; i < 3; ++i) {
    int c = tid + 256 * i;
    float o = ((v[i] - mu) * is * g[c] + b[c]) * keep;
    out[(size_t)row * Hh + c] = o;
  }
}

extern "C" void kernel_launch(void* const* d_in, const int* in_sizes, int n_in,
                              void* d_out, int out_size, void* d_ws, size_t ws_size,
                              hipStream_t stream) {
  const float* token_reps = (const float*)d_in[0];
  const int* span_ids = (const int*)d_in[1];
  const float* dq = (const float*)d_in[2];
  const float* ipw = (const float*)d_in[3];
  const float* ipb = (const float*)d_in[4];
  const float* opw = (const float*)d_in[5];
  const float* opb = (const float*)d_in[6];
  const float* lng = (const float*)d_in[7];
  const float* lnb = (const float*)d_in[8];
  const float* w1 = (const float*)d_in[9];
  const float* b1 = (const float*)d_in[10];
  const float* w2 = (const float*)d_in[11];
  const float* b2 = (const float*)d_in[12];
  float* out = (float*)d_out;

  char* p = (char*)d_ws;
  auto alloc = [&](size_t bytes) { void* r = p; p += (bytes + 255) & ~(size_t)255; return r; };
  short* tokb = (short*)alloc((size_t)NTOK * Hh * 2);
  short* vsw  = (short*)alloc((size_t)NVS * Hh * 2);        // [Wv | qk | 0] bf16
  short* outw = (short*)alloc((size_t)Hh * Hh * 2);
  short* w1b  = (short*)alloc((size_t)FFN_I * Hh * 2);
  short* w2b  = (short*)alloc((size_t)Hh * FFN_I * 2);
  float* qsv  = (float*)alloc(Hh * 4);
  float* bias2= (float*)alloc(Hh * 4);
  float* bvs  = (float*)alloc(NVS * 4);                     // [bv | sb | 0]
  float* S    = (float*)alloc((size_t)NTOK * 12 * 4);       // scores per (tok,h)
  short* Vb   = (short*)alloc((size_t)NTOK * Hh * 2);
  short* ctxb = (short*)alloc((size_t)NSPAN * Hh * 2);
  float* attnY= (float*)alloc((size_t)2 * NSPAN * Hh * 4);  // outproj partials x2
  float* xf   = (float*)alloc((size_t)NSPAN * Hh * 4);
  short* xb   = (short*)alloc((size_t)NSPAN * Hh * 2);
  short* hb   = (short*)alloc((size_t)NSPAN * FFN_I * 2);
  float* y2   = (float*)alloc((size_t)4 * NSPAN * Hh * 4);  // FFN2 partials x4

  // 1. tok = token_reps + pe  (bf16)
  tok_kernel<<<NTOK, 192, 0, stream>>>(token_reps, tokb);
  // 2. fused weight casts + vsw pad zero
  cast4<<<5799, 256, 0, stream>>>(ipw + (size_t)2 * Hh * Hh, opw, w1, w2,
                                  vsw, outw, w1b, w2b);
  // 3. qsv, bias2, bvs(bv|sb|0)
  prep_qb<<<13, 64, 0, stream>>>(dq, ipw, ipb, opb, qsv, bias2, bvs);
  // 4. qk rows (768..779) of vsw
  qk_kernel<<<dim3(12, 12), 64, 0, stream>>>(ipw, qsv, vsw);
  // 5. [V | S] = tok @ vsw^T + bvs   (4096 x 832) — 416 blocks, XCD-clustered
  gemm_bt<4><<<dim3(416, 1), 256, 0, stream>>>(tokb, vsw, bvs, S, Vb,
                                               NTOK, NVS, Hh, Hh, 13, 4);
  // 6. per-span attention (gather S + V) -> ctx
  attn_kernel<<<NSPAN, 384, 0, stream>>>(Vb, S, span_ids, ctxb);
  // 7. attn_out partials = ctx @ Wo^T  (split-K=2)
  gemm_bt<3><<<dim3(192, 2), 256, 0, stream>>>(ctxb, outw, nullptr, attnY, nullptr,
                                               NSPAN, Hh, Hh, Hh / 2, 12, 2);
  // 8. x = LN(sum attnY + (bo + q0))
  ln_kernel<<<NSPAN, 256, 0, stream>>>(attnY, bias2, lng, lnb, xf, xb);
  // 9. h = relu(x @ W1^T + b1)  (bf16)
  gemm_bt<1><<<dim3(768, 1), 256, 0, stream>>>(xb, w1b, b1, nullptr, hb,
                                               NSPAN, FFN_I, Hh, Hh, 48, 2);
  // 10. y2 partials = h @ W2^T  (split-K=4)
  gemm_bt<3><<<dim3(192, 4), 256, 0, stream>>>(hb, w2b, nullptr, y2, nullptr,
                                               NSPAN, Hh, FFN_I, FFN_I / 4, 12, 2);
  // 11. out = LN(sum y2 + b2 + x) masked by len>0
  ln_final<<<NSPAN, 256, 0, stream>>>(y2, b2, xf, lng, lnb, span_ids, out);
}

// Round 8
// 204.168 us; speedup vs baseline: 1.9962x; 1.0301x over previous
//
#include <hip/hip_runtime.h>
#include <hip/hip_bf16.h>
#include <cstdint>

// Problem constants
#define Bb 8
#define SLh 512
#define Hh 768
#define NSs 256
#define Ww 32
#define NHh 12
#define HDd 64
#define FFN_I 3072
#define NTOK (Bb*SLh)      // 4096
#define NSPAN (Bb*NSs)     // 2048
#define NVS 832            // V cols (768) + 12 score cols + pad to 13*64

typedef __attribute__((ext_vector_type(8))) __bf16 bf16x8;
typedef __attribute__((ext_vector_type(4))) float f32x4;

__device__ __forceinline__ short f2bf(float f) {
  unsigned u = __builtin_bit_cast(unsigned, f);
  unsigned r = (u + 0x7fffu + ((u >> 16) & 1u)) >> 16;
  return (short)r;
}
__device__ __forceinline__ float bflo(unsigned u) { return __builtin_bit_cast(float, u << 16); }
__device__ __forceinline__ float bfhi(unsigned u) { return __builtin_bit_cast(float, u & 0xffff0000u); }

__device__ __forceinline__ void gload16(const void* g, void* l) {
  __builtin_amdgcn_global_load_lds(
      (__attribute__((address_space(1))) void*)(const_cast<void*>(g)),
      (__attribute__((address_space(3))) void*)l, 16, 0, 0);
}

// ---------------- tok = token_reps + pos_encoding, cast bf16 ----------------
__global__ __launch_bounds__(192) void tok_kernel(const float* __restrict__ tr,
                                                  short* __restrict__ tok) {
  int row = blockIdx.x;            // 4096 = b*512+s
  int s = row & (SLh - 1);
  int c0 = threadIdx.x * 4;        // 192 threads * 4 = 768
  float4 v = *(const float4*)(tr + (size_t)row * Hh + c0);
  const float kinv = -9.210340371976184f / (float)Hh;  // -ln(10000)/H
  float f0 = __expf((float)c0 * kinv);
  float f1 = __expf((float)(c0 + 2) * kinv);
  float s0, cc0, s1, cc1;
  __sincosf((float)s * f0, &s0, &cc0);
  __sincosf((float)s * f1, &s1, &cc1);
  v.x += s0; v.y += cc0; v.z += s1; v.w += cc1;
  short4 o{f2bf(v.x), f2bf(v.y), f2bf(v.z), f2bf(v.w)};
  *(short4*)(tok + (size_t)row * Hh + c0) = o;
}

// ------- fused f32 -> bf16 cast: Wv, Wo, W1, W2 + zero-fill of vsw pad -------
__global__ __launch_bounds__(256) void cast4(const float* __restrict__ s0,
                                             const float* __restrict__ s1,
                                             const float* __restrict__ s2,
                                             const float* __restrict__ s3,
                                             short* __restrict__ d0,
                                             short* __restrict__ d1,
                                             short* __restrict__ d2,
                                             short* __restrict__ d3) {
  int b = blockIdx.x;
  if (b >= 5760) {                 // zero pad rows 780..831 of vsw
    int i = (b - 5760) * 256 + threadIdx.x;          // 9984 short4
    ((short4*)d0)[149760 + i] = short4{0, 0, 0, 0};  // 780*768/4 = 149760
    return;
  }
  const float* s; short* d; int off;
  if (b < 576)       { s = s0; d = d0; off = b; }
  else if (b < 1152) { s = s1; d = d1; off = b - 576; }
  else if (b < 3456) { s = s2; d = d2; off = b - 1152; }
  else               { s = s3; d = d3; off = b - 3456; }
  int i = off * 256 + threadIdx.x;
  float4 v = ((const float4*)s)[i];
  short4 o{f2bf(v.x), f2bf(v.y), f2bf(v.z), f2bf(v.w)};
  ((short4*)d)[i] = o;
}

// ---- qsv=(Wq q + bq)/8, bias2 = bo + q0, bvs = [bv | sb | 0] (score bias) ----
__global__ __launch_bounds__(64) void prep_qb(const float* __restrict__ dq,
                                              const float* __restrict__ ipw,
                                              const float* __restrict__ ipb,
                                              const float* __restrict__ opb,
                                              float* __restrict__ qsv,
                                              float* __restrict__ bias2,
                                              float* __restrict__ bvs) {
  int b = blockIdx.x, lane = threadIdx.x;
  if (b == 12) { if (lane < 52) bvs[780 + lane] = 0.f; return; }
  int h = b * 64 + lane;                       // 12 blocks * 64 = 768
  const float4* wr = (const float4*)(ipw + (size_t)h * Hh);   // Wq rows
  const float4* qv = (const float4*)dq;
  float acc = 0.f;
  for (int j = 0; j < Hh / 4; ++j) {
    float4 w4 = wr[j], q4 = qv[j];
    acc += w4.x * q4.x + w4.y * q4.y + w4.z * q4.z + w4.w * q4.w;
  }
  acc += ipb[h];
  float qs = acc * 0.125f;                     // / sqrt(64)
  qsv[h] = qs;
  bias2[h] = opb[h] + dq[h];
  bvs[h] = ipb[2 * Hh + h];                    // bv
  float t = qs * ipb[Hh + h];                  // qsv . bk  (head-local reduce)
#pragma unroll
  for (int o = 32; o; o >>= 1) t += __shfl_xor(t, o);
  if (lane == 0) bvs[768 + b] = t;             // sb[h]
}

// ---- qk[h] = Wk_h^T qsv_h, written as bf16 rows 768..779 of vsw ----
__global__ __launch_bounds__(64) void qk_kernel(const float* __restrict__ ipw,
                                                const float* __restrict__ qsv,
                                                short* __restrict__ vsw) {
  int h = blockIdx.x, dc = blockIdx.y, lane = threadIdx.x;
  int d = dc * 64 + lane;
  const float* wk = ipw + (size_t)(Hh + h * 64) * Hh + d;     // Wk rows
  const float* qh = qsv + h * 64;
  float a = 0.f;
#pragma unroll 8
  for (int e = 0; e < 64; ++e) a += qh[e] * wk[(size_t)e * Hh];
  vsw[(size_t)(768 + h) * Hh + d] = f2bf(a);
}

// ---------------- bf16 MFMA GEMM, C = A(MxK) * Bt(NxK)^T ----------------
// 128xBN tile (BN=64 or 128), BK=64, 256 thr (4 waves 2Mx2N).
// DMA staging w/ XOR-swizzled source col (R2/R6-proven, 0 bank conflicts),
// dbuf LDS (48/64 KB -> 3/2 blocks/CU), counted vmcnt. XCD-clustered remap.
// EPI 1: bf16 = relu(acc+bias) ; 3: f32 partial -> Cf + z*M*N ;
// EPI 4: cols<768 -> V bf16 (stride 768); 768<=col<780 -> S f32 (stride 12).
template <int EPI, int BN>
__global__ __launch_bounds__(256, BN == 64 ? 3 : 2)
void gemm_bt(const short* __restrict__ A,
             const short* __restrict__ Bt,
             const float* __restrict__ bias,
             float* __restrict__ Cf,
             short* __restrict__ Cb,
             int M, int N, int ldk, int Kc,
             int nx, int ypp) {
  constexpr int NI = BN / 32;                      // acc cols per wave
  __shared__ __align__(16) char Al[2][128 * 128];
  __shared__ __align__(16) char Bl[2][BN * 128];
  const int tid = threadIdx.x;
  const int lane = tid & 63, wave = tid >> 6;
  const int wm = wave >> 1, wn = wave & 1;
  const int bid = blockIdx.x, xcd = bid & 7, ii = bid >> 3;
  const int iy = ii / nx;
  const int by = xcd * ypp + iy, bx = ii - iy * nx;
  const int row0 = by * 128, col0 = bx * BN;
  const int kbase = blockIdx.y * Kc;
  const int l15 = lane & 15, hi = lane >> 4;
  f32x4 acc[4][NI] = {};
  const int nk = Kc >> 6;
  const int srow = tid >> 3, sslot = tid & 7;

  auto stage = [&](int kt, int bi) {
    const short* Agp = A + (size_t)row0 * ldk + kbase + kt * 64;
    const short* Bgp = Bt + (size_t)col0 * ldk + kbase + kt * 64;
#pragma unroll
    for (int j = 0; j < 4; ++j) {
      int row = j * 32 + srow;
      int col = (sslot ^ (row & 7)) << 3;
      gload16(Agp + (size_t)row * ldk + col,
              &Al[bi][0] + (size_t)(j * 256 + wave * 64) * 16);
    }
#pragma unroll
    for (int j = 0; j < NI; ++j) {
      int row = j * 32 + srow;
      int col = (sslot ^ (row & 7)) << 3;
      gload16(Bgp + (size_t)row * ldk + col,
              &Bl[bi][0] + (size_t)(j * 256 + wave * 64) * 16);
    }
  };

  stage(0, 0);
  for (int kt = 0; kt < nk; ++kt) {
    const int cur = kt & 1;
    if (kt + 1 < nk) {
      stage(kt + 1, cur ^ 1);
      if constexpr (BN == 64)
        asm volatile("s_waitcnt vmcnt(6)" ::: "memory");
      else
        asm volatile("s_waitcnt vmcnt(8)" ::: "memory");
    } else {
      asm volatile("s_waitcnt vmcnt(0)" ::: "memory");
    }
    __builtin_amdgcn_s_barrier();
    asm volatile("" ::: "memory");
    bf16x8 fa[2][4], fb[2][NI];
#pragma unroll
    for (int kk = 0; kk < 2; ++kk) {
#pragma unroll
      for (int i = 0; i < 4; ++i) {
        int Ra = wm * 64 + i * 16 + l15;
        fa[kk][i] = *(const bf16x8*)(&Al[cur][0] + (size_t)Ra * 128 +
                                     (((kk * 4 + hi) ^ (Ra & 7)) << 4));
      }
#pragma unroll
      for (int i = 0; i < NI; ++i) {
        int Rb = wn * (BN / 2) + i * 16 + l15;
        fb[kk][i] = *(const bf16x8*)(&Bl[cur][0] + (size_t)Rb * 128 +
                                     (((kk * 4 + hi) ^ (Rb & 7)) << 4));
      }
    }
#pragma unroll
    for (int kk = 0; kk < 2; ++kk)
#pragma unroll
      for (int mi = 0; mi < 4; ++mi)
#pragma unroll
        for (int ni = 0; ni < NI; ++ni)
          acc[mi][ni] = __builtin_amdgcn_mfma_f32_16x16x32_bf16(fa[kk][mi], fb[kk][ni], acc[mi][ni], 0, 0, 0);
    asm volatile("" ::: "memory");
    __builtin_amdgcn_s_barrier();
  }

  float* dst = (EPI == 3) ? (Cf + (size_t)blockIdx.y * M * N) : Cf;
#pragma unroll
  for (int mi = 0; mi < 4; ++mi) {
#pragma unroll
    for (int ni = 0; ni < NI; ++ni) {
      int colb = col0 + wn * (BN / 2) + ni * 16 + l15;
      float bv = (EPI == 3) ? 0.f : bias[colb];
#pragma unroll
      for (int r = 0; r < 4; ++r) {
        int rowb = row0 + wm * 64 + mi * 16 + hi * 4 + r;
        float v = acc[mi][ni][r] + bv;
        if (EPI == 1) {
          Cb[(size_t)rowb * N + colb] = f2bf(fmaxf(v, 0.f));
        } else if (EPI == 3) {
          dst[(size_t)rowb * N + colb] = v;
        } else {  // EPI 4: V | S split
          if (colb < 768) Cb[(size_t)rowb * 768 + colb] = f2bf(v);
          else if (colb < 780) Cf[(size_t)rowb * 12 + (colb - 768)] = v;
        }
      }
    }
  }
}

// ---------------- per-span attention (scores pre-computed in S) ----------------
// Vb: 4096 x 768 bf16. S: 4096 x 12 f32. ctx: 2048 x 768 bf16.
// XCD-batch clustering: bid&7 -> batch, so each XCD's L2 holds one batch's V.
__global__ __launch_bounds__(384) void attn_kernel(const short* __restrict__ Vb,
                                                   const float* __restrict__ S,
                                                   const int* __restrict__ sid,
                                                   short* __restrict__ ctx) {
  int bid = blockIdx.x;
  int n = ((bid & 7) << 8) | (bid >> 3);   // batch = bid&7, span = bid>>3
  int b = n >> 8;                          // NS=256
  __shared__ int posV[Ww], tS[Ww];
  __shared__ float attnL[NHh][Ww];
  __shared__ int lenS;
  int tid = threadIdx.x;
  if (tid < Ww) {
    int st = sid[2 * n], en = sid[2 * n + 1];
    int p = st + tid;
    p = p < 0 ? 0 : (p > SLh - 1 ? SLh - 1 : p);
    int t = b * SLh + p;
    posV[tid] = t * Hh;
    tS[tid] = t * 12;
    if (tid == 0) lenS = en - st;
  }
  __syncthreads();
  int len = lenS;
  int h = tid >> 5, w = tid & 31;       // 12*32 = 384
  float score = (w < len) ? S[tS[w] + h] : -1e9f;
  float m = score;
#pragma unroll
  for (int o = 16; o; o >>= 1) m = fmaxf(m, __shfl_xor(m, o, 32));
  float e = __expf(score - m);
  float ssum = e;
#pragma unroll
  for (int o = 16; o; o >>= 1) ssum += __shfl_xor(ssum, o, 32);
  attnL[h][w] = e / ssum;
  __syncthreads();
  int hh = tid >> 5, dp = tid & 31;
  float a0 = 0.f, a1 = 0.f;
#pragma unroll
  for (int w2 = 0; w2 < Ww; ++w2) {
    float aw = attnL[hh][w2];
    unsigned u = *(const unsigned*)(Vb + posV[w2] + hh * HDd + 2 * dp);
    a0 += aw * bflo(u);
    a1 += aw * bfhi(u);
  }
  unsigned packed = (unsigned)(unsigned short)f2bf(a0) | ((unsigned)(unsigned short)f2bf(a1) << 16);
  ((unsigned*)ctx)[(size_t)n * (Hh / 2) + tid] = packed;
}

// ---------------- LN over (2 partials + bias2), out f32 + bf16 ----------------
__global__ __launch_bounds__(256) void ln_kernel(const float* __restrict__ Y2,
                                                 const float* __restrict__ bias2,
                                                 const float* __restrict__ g,
                                                 const float* __restrict__ b,
                                                 float* __restrict__ xf,
                                                 short* __restrict__ xb) {
  const size_t SL = (size_t)NSPAN * Hh;
  int row = blockIdx.x;
  int tid = threadIdx.x;
  float v[3]; float s1 = 0.f, s2 = 0.f;
#pragma unroll
  for (int i = 0; i < 3; ++i) {
    int c = tid + 256 * i;
    size_t idx = (size_t)row * Hh + c;
    v[i] = Y2[idx] + Y2[idx + SL] + bias2[c];
    s1 += v[i]; s2 += v[i] * v[i];
  }
  __shared__ float r1[4], r2[4];
#pragma unroll
  for (int o = 32; o; o >>= 1) { s1 += __shfl_xor(s1, o); s2 += __shfl_xor(s2, o); }
  int lane = tid & 63, wv = tid >> 6;
  if (lane == 0) { r1[wv] = s1; r2[wv] = s2; }
  __syncthreads();
  s1 = r1[0] + r1[1] + r1[2] + r1[3];
  s2 = r2[0] + r2[1] + r2[2] + r2[3];
  float mu = s1 * (1.f / Hh);
  float var = s2 * (1.f / Hh) - mu * mu;
  float is = rsqrtf(var + 1e-5f);
#pragma unroll
  for (int i = 0; i < 3; ++i) {
    int c = tid + 256 * i;
    float o = (v[i] - mu) * is * g[c] + b[c];
    xf[(size_t)row * Hh + c] = o;
    xb[(size_t)row * Hh + c] = f2bf(o);
  }
}

// ---------------- final LN over (4 partials + b2 + x) + mask ----------------
__global__ __launch_bounds__(256) void ln_final(const float* __restrict__ Y4,
                                                const float* __restrict__ b2,
                                                const float* __restrict__ xf,
                                                const float* __restrict__ g,
                                                const float* __restrict__ b,
                                                const int* __restrict__ sid,
                                                float* __restrict__ out) {
  const size_t SL = (size_t)NSPAN * Hh;
  int row = blockIdx.x;
  int len = sid[2 * row + 1] - sid[2 * row];
  int tid = threadIdx.x;
  float v[3]; float s1 = 0.f, s2 = 0.f;
#pragma unroll
  for (int i = 0; i < 3; ++i) {
    int c = tid + 256 * i;
    size_t idx = (size_t)row * Hh + c;
    v[i] = Y4[idx] + Y4[idx + SL] + Y4[idx + 2 * SL] + Y4[idx + 3 * SL]
         + b2[c] + xf[idx];
    s1 += v[i]; s2 += v[i] * v[i];
  }
  __shared__ float r1[4], r2[4];
#pragma unroll
  for (int o = 32; o; o >>= 1) { s1 += __shfl_xor(s1, o); s2 += __shfl_xor(s2, o); }
  int lane = tid & 63, wv = tid >> 6;
  if (lane == 0) { r1[wv] = s1; r2[wv] = s2; }
  __syncthreads();
  s1 = r1[0] + r1[1] + r1[2] + r1[3];
  s2 = r2[0] + r2[1] + r2[2] + r2[3];
  float mu = s1 * (1.f / Hh);
  float var = s2 * (1.f / Hh) - mu * mu;
  float is = rsqrtf(var + 1e-5f);
  float keep = (len > 0) ? 1.f : 0.f;
#pragma unroll
  for (int i = 0; i < 3; ++i) {
    int c = tid + 256 * i;
    float o = ((v[i] - mu) * is * g[c] + b[c]) * keep;
    out[(size_t)row * Hh + c] = o;
  }
}

extern "C" void kernel_launch(void* const* d_in, const int* in_sizes, int n_in,
                              void* d_out, int out_size, void* d_ws, size_t ws_size,
                              hipStream_t stream) {
  const float* token_reps = (const float*)d_in[0];
  const int* span_ids = (const int*)d_in[1];
  const float* dq = (const float*)d_in[2];
  const float* ipw = (const float*)d_in[3];
  const float* ipb = (const float*)d_in[4];
  const float* opw = (const float*)d_in[5];
  const float* opb = (const float*)d_in[6];
  const float* lng = (const float*)d_in[7];
  const float* lnb = (const float*)d_in[8];
  const float* w1 = (const float*)d_in[9];
  const float* b1 = (const float*)d_in[10];
  const float* w2 = (const float*)d_in[11];
  const float* b2 = (const float*)d_in[12];
  float* out = (float*)d_out;

  char* p = (char*)d_ws;
  auto alloc = [&](size_t bytes) { void* r = p; p += (bytes + 255) & ~(size_t)255; return r; };
  short* tokb = (short*)alloc((size_t)NTOK * Hh * 2);
  short* vsw  = (short*)alloc((size_t)NVS * Hh * 2);        // [Wv | qk | 0] bf16
  short* outw = (short*)alloc((size_t)Hh * Hh * 2);
  short* w1b  = (short*)alloc((size_t)FFN_I * Hh * 2);
  short* w2b  = (short*)alloc((size_t)Hh * FFN_I * 2);
  float* qsv  = (float*)alloc(Hh * 4);
  float* bias2= (float*)alloc(Hh * 4);
  float* bvs  = (float*)alloc(NVS * 4);                     // [bv | sb | 0]
  float* S    = (float*)alloc((size_t)NTOK * 12 * 4);       // scores per (tok,h)
  short* Vb   = (short*)alloc((size_t)NTOK * Hh * 2);
  short* ctxb = (short*)alloc((size_t)NSPAN * Hh * 2);
  float* attnY= (float*)alloc((size_t)2 * NSPAN * Hh * 4);  // outproj partials x2
  float* xf   = (float*)alloc((size_t)NSPAN * Hh * 4);
  short* xb   = (short*)alloc((size_t)NSPAN * Hh * 2);
  short* hb   = (short*)alloc((size_t)NSPAN * FFN_I * 2);
  float* y2   = (float*)alloc((size_t)4 * NSPAN * Hh * 4);  // FFN2 partials x4

  // 1. tok = token_reps + pe  (bf16)
  tok_kernel<<<NTOK, 192, 0, stream>>>(token_reps, tokb);
  // 2. fused weight casts + vsw pad zero
  cast4<<<5799, 256, 0, stream>>>(ipw + (size_t)2 * Hh * Hh, opw, w1, w2,
                                  vsw, outw, w1b, w2b);
  // 3. qsv, bias2, bvs(bv|sb|0)
  prep_qb<<<13, 64, 0, stream>>>(dq, ipw, ipb, opb, qsv, bias2, bvs);
  // 4. qk rows (768..779) of vsw
  qk_kernel<<<dim3(12, 12), 64, 0, stream>>>(ipw, qsv, vsw);
  // 5. [V | S] = tok @ vsw^T + bvs   (4096 x 832) — 416 blocks, XCD-clustered
  gemm_bt<4, 64><<<dim3(416, 1), 256, 0, stream>>>(tokb, vsw, bvs, S, Vb,
                                                   NTOK, NVS, Hh, Hh, 13, 4);
  // 6. per-span attention (gather S + V) -> ctx
  attn_kernel<<<NSPAN, 384, 0, stream>>>(Vb, S, span_ids, ctxb);
  // 7. attn_out partials = ctx @ Wo^T  (split-K=2)
  gemm_bt<3, 64><<<dim3(192, 2), 256, 0, stream>>>(ctxb, outw, nullptr, attnY, nullptr,
                                                   NSPAN, Hh, Hh, Hh / 2, 12, 2);
  // 8. x = LN(sum attnY + (bo + q0))
  ln_kernel<<<NSPAN, 256, 0, stream>>>(attnY, bias2, lng, lnb, xf, xb);
  // 9. h = relu(x @ W1^T + b1)  (bf16) — 128x128 tile, 384 blocks
  gemm_bt<1, 128><<<dim3(384, 1), 256, 0, stream>>>(xb, w1b, b1, nullptr, hb,
                                                    NSPAN, FFN_I, Hh, Hh, 24, 2);
  // 10. y2 partials = h @ W2^T  (split-K=4) — 128x128 tile, 96x4 blocks
  gemm_bt<3, 128><<<dim3(96, 4), 256, 0, stream>>>(hb, w2b, nullptr, y2, nullptr,
                                                   NSPAN, Hh, FFN_I, FFN_I / 4, 6, 2);
  // 11. out = LN(sum y2 + b2 + x) masked by len>0
  ln_final<<<NSPAN, 256, 0, stream>>>(y2, b2, xf, lng, lnb, span_ids, out);
}

// Round 9
// 200.331 us; speedup vs baseline: 2.0344x; 1.0192x over previous
//
#include <hip/hip_runtime.h>
#include <hip/hip_bf16.h>
#include <cstdint>

// Problem constants
#define Bb 8
#define SLh 512
#define Hh 768
#define NSs 256
#define Ww 32
#define NHh 12
#define HDd 64
#define FFN_I 3072
#define NTOK (Bb*SLh)      // 4096
#define NSPAN (Bb*NSs)     // 2048
#define NVS 832            // V cols (768) + 12 score cols + pad to 13*64

typedef __attribute__((ext_vector_type(8))) __bf16 bf16x8;
typedef __attribute__((ext_vector_type(4))) float f32x4;

__device__ __forceinline__ short f2bf(float f) {
  unsigned u = __builtin_bit_cast(unsigned, f);
  unsigned r = (u + 0x7fffu + ((u >> 16) & 1u)) >> 16;
  return (short)r;
}
__device__ __forceinline__ float bflo(unsigned u) { return __builtin_bit_cast(float, u << 16); }
__device__ __forceinline__ float bfhi(unsigned u) { return __builtin_bit_cast(float, u & 0xffff0000u); }

__device__ __forceinline__ void gload16(const void* g, void* l) {
  __builtin_amdgcn_global_load_lds(
      (__attribute__((address_space(1))) void*)(const_cast<void*>(g)),
      (__attribute__((address_space(3))) void*)l, 16, 0, 0);
}

// ------ fused prep: tok=tr+PE (bf16) | casts Wv,Wo,W1,W2 | vsw pad zero ------
// blocks: [0,3072) tok ; [3072,3648) Wv->vsw ; [3648,4224) Wo ;
//         [4224,6528) W1 ; [6528,8832) W2 ; [8832,8871) zero vsw rows 780..831
__global__ __launch_bounds__(256) void prep_all(const float* __restrict__ tr,
                                                const float* __restrict__ wv,
                                                const float* __restrict__ wo,
                                                const float* __restrict__ w1,
                                                const float* __restrict__ w2,
                                                short* __restrict__ tok,
                                                short* __restrict__ vsw,
                                                short* __restrict__ outw,
                                                short* __restrict__ w1b,
                                                short* __restrict__ w2b) {
  int b = blockIdx.x, tid = threadIdx.x;
  if (b < 3072) {                    // tok = token_reps + PE
    int i4 = b * 256 + tid;          // float4 index
    int row = i4 / 192;              // token id
    int c0 = (i4 - row * 192) * 4;   // column
    int s = row & (SLh - 1);
    float4 v = ((const float4*)tr)[i4];
    const float kinv = -9.210340371976184f / (float)Hh;
    float f0 = __expf((float)c0 * kinv);
    float f1 = __expf((float)(c0 + 2) * kinv);
    float s0, cc0, s1, cc1;
    __sincosf((float)s * f0, &s0, &cc0);
    __sincosf((float)s * f1, &s1, &cc1);
    v.x += s0; v.y += cc0; v.z += s1; v.w += cc1;
    ((short4*)tok)[i4] = short4{f2bf(v.x), f2bf(v.y), f2bf(v.z), f2bf(v.w)};
    return;
  }
  if (b >= 8832) {                   // zero pad rows 780..831 of vsw
    int i = (b - 8832) * 256 + tid;  // 9984 short4
    ((short4*)vsw)[149760 + i] = short4{0, 0, 0, 0};
    return;
  }
  const float* s; short* d; int off;
  if (b < 3648)      { s = wv; d = vsw;  off = b - 3072; }
  else if (b < 4224) { s = wo; d = outw; off = b - 3648; }
  else if (b < 6528) { s = w1; d = w1b;  off = b - 4224; }
  else               { s = w2; d = w2b;  off = b - 6528; }
  int i = off * 256 + tid;
  float4 v = ((const float4*)s)[i];
  ((short4*)d)[i] = short4{f2bf(v.x), f2bf(v.y), f2bf(v.z), f2bf(v.w)};
}

// ---- fused qk/bias prep. grid (12 heads, 13): dc<12 -> qk row chunk of vsw;
// dc==12 -> bias2 = bo+q0, bvs = [bv | sb | 0]. Each block recomputes its
// head's qsv (64 dots of 768) locally — Wq re-reads are L2-hits.
__global__ __launch_bounds__(64) void qkprep(const float* __restrict__ dq,
                                             const float* __restrict__ ipw,
                                             const float* __restrict__ ipb,
                                             const float* __restrict__ opb,
                                             float* __restrict__ bias2,
                                             float* __restrict__ bvs,
                                             short* __restrict__ vsw) {
  int h = blockIdx.x, dc = blockIdx.y, lane = threadIdx.x;
  int hl = h * 64 + lane;
  const float4* wr = (const float4*)(ipw + (size_t)hl * Hh);   // Wq row hl
  const float4* qv = (const float4*)dq;
  float acc = 0.f;
  for (int j = 0; j < Hh / 4; ++j) {
    float4 w4 = wr[j], q4 = qv[j];
    acc += w4.x * q4.x + w4.y * q4.y + w4.z * q4.z + w4.w * q4.w;
  }
  float qs = (acc + ipb[hl]) * 0.125f;         // qsv_h[lane]
  if (dc == 12) {
    bias2[hl] = opb[hl] + dq[hl];
    bvs[hl] = ipb[2 * Hh + hl];                // bv
    float t = qs * ipb[Hh + hl];               // qsv . bk (head-local)
#pragma unroll
    for (int o = 32; o; o >>= 1) t += __shfl_xor(t, o);
    if (lane == 0) bvs[768 + h] = t;           // sb[h]
    if (h == 0 && lane < 52) bvs[780 + lane] = 0.f;
    return;
  }
  __shared__ float qh[64];
  qh[lane] = qs;
  __syncthreads();
  int d = dc * 64 + lane;
  const float* wk = ipw + (size_t)(Hh + h * 64) * Hh + d;      // Wk rows
  float a = 0.f;
#pragma unroll 8
  for (int e = 0; e < 64; ++e) a += qh[e] * wk[(size_t)e * Hh];
  vsw[(size_t)(768 + h) * Hh + d] = f2bf(a);
}

// ---------------- bf16 MFMA GEMM, C = A(MxK) * Bt(NxK)^T ----------------
// BMxBN tile, BK=64, 256 thr (4 waves 2Mx2N). DMA staging w/ XOR-swizzled
// source col (R2/R6-proven, 0 bank conflicts), dbuf 48 KB -> 3 blocks/CU,
// counted vmcnt(6). XCD-clustered remap: xcd=bid&7 owns ypp row-panels.
// EPI 1: bf16 = relu(acc+bias) ; 3: f32 partial -> Cf + z*M*N ;
// EPI 4: cols<768 -> V bf16 (stride 768); 768<=col<780 -> S f32 (stride 12).
template <int EPI, int BM, int BN>
__global__ __launch_bounds__(256, 3)
void gemm_bt(const short* __restrict__ A,
             const short* __restrict__ Bt,
             const float* __restrict__ bias,
             float* __restrict__ Cf,
             short* __restrict__ Cb,
             int M, int N, int ldk, int Kc,
             int nx, int ypp) {
  constexpr int MI = BM / 32, NI = BN / 32;       // acc frags per wave
  __shared__ __align__(16) char Al[2][BM * 128];
  __shared__ __align__(16) char Bl[2][BN * 128];
  const int tid = threadIdx.x;
  const int lane = tid & 63, wave = tid >> 6;
  const int wm = wave >> 1, wn = wave & 1;
  const int bid = blockIdx.x, xcd = bid & 7, ii = bid >> 3;
  const int iy = ii / nx;
  const int by = xcd * ypp + iy, bx = ii - iy * nx;
  const int row0 = by * BM, col0 = bx * BN;
  const int kbase = blockIdx.y * Kc;
  const int l15 = lane & 15, hi = lane >> 4;
  f32x4 acc[MI][NI] = {};
  const int nk = Kc >> 6;
  const int srow = tid >> 3, sslot = tid & 7;

  auto stage = [&](int kt, int bi) {
    const short* Agp = A + (size_t)row0 * ldk + kbase + kt * 64;
    const short* Bgp = Bt + (size_t)col0 * ldk + kbase + kt * 64;
#pragma unroll
    for (int j = 0; j < MI; ++j) {
      int row = j * 32 + srow;
      int col = (sslot ^ (row & 7)) << 3;
      gload16(Agp + (size_t)row * ldk + col,
              &Al[bi][0] + (size_t)(j * 256 + wave * 64) * 16);
    }
#pragma unroll
    for (int j = 0; j < NI; ++j) {
      int row = j * 32 + srow;
      int col = (sslot ^ (row & 7)) << 3;
      gload16(Bgp + (size_t)row * ldk + col,
              &Bl[bi][0] + (size_t)(j * 256 + wave * 64) * 16);
    }
  };

  stage(0, 0);
  for (int kt = 0; kt < nk; ++kt) {
    const int cur = kt & 1;
    if (kt + 1 < nk) {
      stage(kt + 1, cur ^ 1);
      asm volatile("s_waitcnt vmcnt(6)" ::: "memory");   // MI+NI==6 both shapes
    } else {
      asm volatile("s_waitcnt vmcnt(0)" ::: "memory");
    }
    __builtin_amdgcn_s_barrier();
    asm volatile("" ::: "memory");
    bf16x8 fa[2][MI], fb[2][NI];
#pragma unroll
    for (int kk = 0; kk < 2; ++kk) {
#pragma unroll
      for (int i = 0; i < MI; ++i) {
        int Ra = wm * (BM / 2) + i * 16 + l15;
        fa[kk][i] = *(const bf16x8*)(&Al[cur][0] + (size_t)Ra * 128 +
                                     (((kk * 4 + hi) ^ (Ra & 7)) << 4));
      }
#pragma unroll
      for (int i = 0; i < NI; ++i) {
        int Rb = wn * (BN / 2) + i * 16 + l15;
        fb[kk][i] = *(const bf16x8*)(&Bl[cur][0] + (size_t)Rb * 128 +
                                     (((kk * 4 + hi) ^ (Rb & 7)) << 4));
      }
    }
#pragma unroll
    for (int kk = 0; kk < 2; ++kk)
#pragma unroll
      for (int mi = 0; mi < MI; ++mi)
#pragma unroll
        for (int ni = 0; ni < NI; ++ni)
          acc[mi][ni] = __builtin_amdgcn_mfma_f32_16x16x32_bf16(fa[kk][mi], fb[kk][ni], acc[mi][ni], 0, 0, 0);
    asm volatile("" ::: "memory");
    __builtin_amdgcn_s_barrier();
  }

  float* dst = (EPI == 3) ? (Cf + (size_t)blockIdx.y * M * N) : Cf;
#pragma unroll
  for (int mi = 0; mi < MI; ++mi) {
#pragma unroll
    for (int ni = 0; ni < NI; ++ni) {
      int colb = col0 + wn * (BN / 2) + ni * 16 + l15;
      float bv = (EPI == 3) ? 0.f : bias[colb];
#pragma unroll
      for (int r = 0; r < 4; ++r) {
        int rowb = row0 + wm * (BM / 2) + mi * 16 + hi * 4 + r;
        float v = acc[mi][ni][r] + bv;
        if (EPI == 1) {
          Cb[(size_t)rowb * N + colb] = f2bf(fmaxf(v, 0.f));
        } else if (EPI == 3) {
          dst[(size_t)rowb * N + colb] = v;
        } else {  // EPI 4: V | S split
          if (colb < 768) Cb[(size_t)rowb * 768 + colb] = f2bf(v);
          else if (colb < 780) Cf[(size_t)rowb * 12 + (colb - 768)] = v;
        }
      }
    }
  }
}

// ---------------- per-span attention (scores pre-computed in S) ----------------
// Vb: 4096 x 768 bf16. S: 4096 x 12 f32. ctx: 2048 x 768 bf16.
// XCD-batch clustering: bid&7 -> batch, so each XCD's L2 holds one batch's V.
__global__ __launch_bounds__(384) void attn_kernel(const short* __restrict__ Vb,
                                                   const float* __restrict__ S,
                                                   const int* __restrict__ sid,
                                                   short* __restrict__ ctx) {
  int bid = blockIdx.x;
  int n = ((bid & 7) << 8) | (bid >> 3);   // batch = bid&7, span = bid>>3
  int b = n >> 8;                          // NS=256
  __shared__ int posV[Ww], tS[Ww];
  __shared__ float attnL[NHh][Ww];
  __shared__ int lenS;
  int tid = threadIdx.x;
  if (tid < Ww) {
    int st = sid[2 * n], en = sid[2 * n + 1];
    int p = st + tid;
    p = p < 0 ? 0 : (p > SLh - 1 ? SLh - 1 : p);
    int t = b * SLh + p;
    posV[tid] = t * Hh;
    tS[tid] = t * 12;
    if (tid == 0) lenS = en - st;
  }
  __syncthreads();
  int len = lenS;
  int h = tid >> 5, w = tid & 31;       // 12*32 = 384
  float score = (w < len) ? S[tS[w] + h] : -1e9f;
  float m = score;
#pragma unroll
  for (int o = 16; o; o >>= 1) m = fmaxf(m, __shfl_xor(m, o, 32));
  float e = __expf(score - m);
  float ssum = e;
#pragma unroll
  for (int o = 16; o; o >>= 1) ssum += __shfl_xor(ssum, o, 32);
  attnL[h][w] = e / ssum;
  __syncthreads();
  int hh = tid >> 5, dp = tid & 31;
  float a0 = 0.f, a1 = 0.f;
#pragma unroll
  for (int w2 = 0; w2 < Ww; ++w2) {
    float aw = attnL[hh][w2];
    unsigned u = *(const unsigned*)(Vb + posV[w2] + hh * HDd + 2 * dp);
    a0 += aw * bflo(u);
    a1 += aw * bfhi(u);
  }
  unsigned packed = (unsigned)(unsigned short)f2bf(a0) | ((unsigned)(unsigned short)f2bf(a1) << 16);
  ((unsigned*)ctx)[(size_t)n * (Hh / 2) + tid] = packed;
}

// ---------------- LN over (4 partials + bias2), out f32 + bf16 ----------------
__global__ __launch_bounds__(256) void ln_kernel(const float* __restrict__ Y4,
                                                 const float* __restrict__ bias2,
                                                 const float* __restrict__ g,
                                                 const float* __restrict__ b,
                                                 float* __restrict__ xf,
                                                 short* __restrict__ xb) {
  const size_t SL = (size_t)NSPAN * Hh;
  int row = blockIdx.x;
  int tid = threadIdx.x;
  float v[3]; float s1 = 0.f, s2 = 0.f;
#pragma unroll
  for (int i = 0; i < 3; ++i) {
    int c = tid + 256 * i;
    size_t idx = (size_t)row * Hh + c;
    v[i] = Y4[idx] + Y4[idx + SL] + Y4[idx + 2 * SL] + Y4[idx + 3 * SL] + bias2[c];
    s1 += v[i]; s2 += v[i] * v[i];
  }
  __shared__ float r1[4], r2[4];
#pragma unroll
  for (int o = 32; o; o >>= 1) { s1 += __shfl_xor(s1, o); s2 += __shfl_xor(s2, o); }
  int lane = tid & 63, wv = tid >> 6;
  if (lane == 0) { r1[wv] = s1; r2[wv] = s2; }
  __syncthreads();
  s1 = r1[0] + r1[1] + r1[2] + r1[3];
  s2 = r2[0] + r2[1] + r2[2] + r2[3];
  float mu = s1 * (1.f / Hh);
  float var = s2 * (1.f / Hh) - mu * mu;
  float is = rsqrtf(var + 1e-5f);
#pragma unroll
  for (int i = 0; i < 3; ++i) {
    int c = tid + 256 * i;
    float o = (v[i] - mu) * is * g[c] + b[c];
    xf[(size_t)row * Hh + c] = o;
    xb[(size_t)row * Hh + c] = f2bf(o);
  }
}

// ---------------- final LN over (4 partials + b2 + x) + mask ----------------
__global__ __launch_bounds__(256) void ln_final(const float* __restrict__ Y4,
                                                const float* __restrict__ b2,
                                                const float* __restrict__ xf,
                                                const float* __restrict__ g,
                                                const float* __restrict__ b,
                                                const int* __restrict__ sid,
                                                float* __restrict__ out) {
  const size_t SL = (size_t)NSPAN * Hh;
  int row = blockIdx.x;
  int len = sid[2 * row + 1] - sid[2 * row];
  int tid = threadIdx.x;
  float v[3]; float s1 = 0.f, s2 = 0.f;
#pragma unroll
  for (int i = 0; i < 3; ++i) {
    int c = tid + 256 * i;
    size_t idx = (size_t)row * Hh + c;
    v[i] = Y4[idx] + Y4[idx + SL] + Y4[idx + 2 * SL] + Y4[idx + 3 * SL]
         + b2[c] + xf[idx];
    s1 += v[i]; s2 += v[i] * v[i];
  }
  __shared__ float r1[4], r2[4];
#pragma unroll
  for (int o = 32; o; o >>= 1) { s1 += __shfl_xor(s1, o); s2 += __shfl_xor(s2, o); }
  int lane = tid & 63, wv = tid >> 6;
  if (lane == 0) { r1[wv] = s1; r2[wv] = s2; }
  __syncthreads();
  s1 = r1[0] + r1[1] + r1[2] + r1[3];
  s2 = r2[0] + r2[1] + r2[2] + r2[3];
  float mu = s1 * (1.f / Hh);
  float var = s2 * (1.f / Hh) - mu * mu;
  float is = rsqrtf(var + 1e-5f);
  float keep = (len > 0) ? 1.f : 0.f;
#pragma unroll
  for (int i = 0; i < 3; ++i) {
    int c = tid + 256 * i;
    float o = ((v[i] - mu) * is * g[c] + b[c]) * keep;
    out[(size_t)row * Hh + c] = o;
  }
}

extern "C" void kernel_launch(void* const* d_in, const int* in_sizes, int n_in,
                              void* d_out, int out_size, void* d_ws, size_t ws_size,
                              hipStream_t stream) {
  const float* token_reps = (const float*)d_in[0];
  const int* span_ids = (const int*)d_in[1];
  const float* dq = (const float*)d_in[2];
  const float* ipw = (const float*)d_in[3];
  const float* ipb = (const float*)d_in[4];
  const float* opw = (const float*)d_in[5];
  const float* opb = (const float*)d_in[6];
  const float* lng = (const float*)d_in[7];
  const float* lnb = (const float*)d_in[8];
  const float* w1 = (const float*)d_in[9];
  const float* b1 = (const float*)d_in[10];
  const float* w2 = (const float*)d_in[11];
  const float* b2 = (const float*)d_in[12];
  float* out = (float*)d_out;

  char* p = (char*)d_ws;
  auto alloc = [&](size_t bytes) { void* r = p; p += (bytes + 255) & ~(size_t)255; return r; };
  short* tokb = (short*)alloc((size_t)NTOK * Hh * 2);
  short* vsw  = (short*)alloc((size_t)NVS * Hh * 2);        // [Wv | qk | 0] bf16
  short* outw = (short*)alloc((size_t)Hh * Hh * 2);
  short* w1b  = (short*)alloc((size_t)FFN_I * Hh * 2);
  short* w2b  = (short*)alloc((size_t)Hh * FFN_I * 2);
  float* bias2= (float*)alloc(Hh * 4);
  float* bvs  = (float*)alloc(NVS * 4);                     // [bv | sb | 0]
  float* S    = (float*)alloc((size_t)NTOK * 12 * 4);       // scores per (tok,h)
  short* Vb   = (short*)alloc((size_t)NTOK * Hh * 2);
  short* ctxb = (short*)alloc((size_t)NSPAN * Hh * 2);
  float* attnY= (float*)alloc((size_t)4 * NSPAN * Hh * 4);  // outproj partials x4
  float* xf   = (float*)alloc((size_t)NSPAN * Hh * 4);
  short* xb   = (short*)alloc((size_t)NSPAN * Hh * 2);
  short* hb   = (short*)alloc((size_t)NSPAN * FFN_I * 2);
  float* y2   = (float*)alloc((size_t)4 * NSPAN * Hh * 4);  // FFN2 partials x4

  // 1. fused prep: tok+PE, weight casts, vsw pad
  prep_all<<<8871, 256, 0, stream>>>(token_reps, ipw + (size_t)2 * Hh * Hh, opw,
                                     w1, w2, tokb, vsw, outw, w1b, w2b);
  // 2. fused qk rows + bias2/bvs
  qkprep<<<dim3(12, 13), 64, 0, stream>>>(dq, ipw, ipb, opb, bias2, bvs, vsw);
  // 3. [V | S] = tok @ vsw^T + bvs   (4096 x 832) — 416 blocks, XCD-clustered
  gemm_bt<4, 128, 64><<<dim3(416, 1), 256, 0, stream>>>(tokb, vsw, bvs, S, Vb,
                                                        NTOK, NVS, Hh, Hh, 13, 4);
  // 4. per-span attention (gather S + V) -> ctx
  attn_kernel<<<NSPAN, 384, 0, stream>>>(Vb, S, span_ids, ctxb);
  // 5. attn_out partials = ctx @ Wo^T  (split-K=4, 192x4 = 768 even)
  gemm_bt<3, 128, 64><<<dim3(192, 4), 256, 0, stream>>>(ctxb, outw, nullptr, attnY, nullptr,
                                                        NSPAN, Hh, Hh, Hh / 4, 12, 2);
  // 6. x = LN(sum attnY + (bo + q0))
  ln_kernel<<<NSPAN, 256, 0, stream>>>(attnY, bias2, lng, lnb, xf, xb);
  // 7. h = relu(x @ W1^T + b1)  — 64x128 tile, 32x24 = 768 even (3/CU)
  gemm_bt<1, 64, 128><<<dim3(768, 1), 256, 0, stream>>>(xb, w1b, b1, nullptr, hb,
                                                        NSPAN, FFN_I, Hh, Hh, 24, 4);
  // 8. y2 partials = h @ W2^T  (split-K=4) — 64x128 tile, 192x4 = 768 even
  gemm_bt<3, 64, 128><<<dim3(192, 4), 256, 0, stream>>>(hb, w2b, nullptr, y2, nullptr,
                                                        NSPAN, Hh, FFN_I, FFN_I / 4, 6, 4);
  // 9. out = LN(sum y2 + b2 + x) masked by len>0
  ln_final<<<NSPAN, 256, 0, stream>>>(y2, b2, xf, lng, lnb, span_ids, out);
}